// Round 2
// baseline (424.597 us; speedup 1.0000x reference)
//
#include <hip/hip_runtime.h>
#include <cstdint>
#include <cstddef>

namespace {

constexpr float kScale = 0.03608439182435161f; // 768^-0.5
constexpr float kEps   = 1e-5f;

// workspace offsets (in floats)
constexpr size_t OFF_QK0T = 0;                       // 12*768
constexpr size_t OFF_QBK0 = 9216;                    // 12
constexpr size_t OFF_S    = 16384;                   // 320*12*768 (s0, later s1)
constexpr size_t OFF_QK1  = OFF_S   + 2949120;       // 320*12*768
constexpr size_t OFF_O    = OFF_QK1 + 2949120;       // 320*768
constexpr size_t OFF_U    = OFF_O   + 245760;
constexpr size_t OFF_X    = OFF_U   + 245760;
constexpr size_t OFF_QF1  = OFF_X   + 245760;
constexpr size_t OFF_H1   = OFF_QF1 + 245760;
constexpr size_t OFF_H2   = OFF_H1  + 245760;
constexpr size_t OFF_WF   = OFF_H2  + 245760;        // bf16 frag weights (shorts)

constexpr size_t WF_MAT_SHORTS = 1179648;            // 24*48*2*64*8

typedef short short8v __attribute__((ext_vector_type(8)));
typedef float float4v __attribute__((ext_vector_type(4)));

union BP  { int4 i4; short8v s8; };
union S4P { int2 i2; short s[4]; };

__device__ __forceinline__ void splitBf(float a, short &h, short &l){
    unsigned u = __float_as_uint(a);
    h = (short)(u >> 16);
    float r = a - __uint_as_float(u & 0xFFFF0000u);
    l = (short)(__float_as_uint(r) >> 16);
}

__device__ __forceinline__ float Gf(float t){
    float tc = fminf(fmaxf(t, -1.f), 1.f);
    return 0.5f + tc * (1.f - 0.5f * fabsf(tc));
}

__device__ __forceinline__ float blockReduce256(float v, float* red){
    #pragma unroll
    for (int off = 1; off < 64; off <<= 1) v += __shfl_xor(v, off);
    __syncthreads();
    if ((threadIdx.x & 63) == 0) red[threadIdx.x >> 6] = v;
    __syncthreads();
    return red[0] + red[1] + red[2] + red[3];
}

// ---------------------------------------------------------------------------
// k_wprep: convert 7 weight matrices (768x768 fp32, row-major [k][n]) into
// MFMA fragment-ordered bf16 hi/lo: WF[mat][kt(24)][nb(48)][hl(2)][lane(64)][e(8)]
// frag mapping (16x16x32 bf16): k = kt*32 + (l>>4)*4 + (e&3) + 16*(e>>2),
//                               n = nb*16 + (l&15)
// ---------------------------------------------------------------------------
__global__ __launch_bounds__(256) void k_wprep(
        const float* __restrict__ w0, const float* __restrict__ w1,
        const float* __restrict__ w2, const float* __restrict__ w3,
        const float* __restrict__ w4, const float* __restrict__ w5,
        const float* __restrict__ w6, short* __restrict__ WF){
    const float* Wsel[7] = {w0,w1,w2,w3,w4,w5,w6};
    const float* W = Wsel[blockIdx.y];
    const int unit = blockIdx.x * 4 + (threadIdx.x >> 6); // 0..1151
    const int l = threadIdx.x & 63;
    const int kt = unit / 48, nb = unit % 48;
    const int n = nb*16 + (l & 15);
    const int kb = kt*32 + ((l >> 4) << 2);
    S4P hi0, hi1, lo0, lo1;
    #pragma unroll
    for (int e = 0; e < 4; ++e){
        float a = W[(size_t)(kb + e) * 768 + n];
        splitBf(a, hi0.s[e], lo0.s[e]);
        float b = W[(size_t)(kb + 16 + e) * 768 + n];
        splitBf(b, hi1.s[e], lo1.s[e]);
    }
    size_t base = (size_t)blockIdx.y * WF_MAT_SHORTS + (size_t)unit * 1024 + (size_t)l * 8;
    *(int2*)(WF + base)            = hi0.i2;
    *(int2*)(WF + base + 4)        = hi1.i2;
    *(int2*)(WF + base + 512)      = lo0.i2;
    *(int2*)(WF + base + 512 + 4)  = lo1.i2;
}

// ---------------------------------------------------------------------------
// k_mgemm: C[m][n] = act(bias[n] + A[320x768] @ W[768x768]) via bf16 hi/lo MFMA
// grid (10, 12): 32x64 tile. 4 waves = 2m x 2n. K-step 32, 3 MFMA per frag pair.
// HG: A row = (m*12 + blockIdx.y)*768 (head-gathered s buffer).
// ---------------------------------------------------------------------------
template<int HG, int RELU>
__global__ __launch_bounds__(256) void k_mgemm(
        const float* __restrict__ A, const short* __restrict__ WFm,
        const float* __restrict__ bias, float* __restrict__ C){
    __shared__ short AF[2][2][2][64][8]; // [buf][fm][hl][lane][e]
    const int h   = blockIdx.y;
    const int m0  = blockIdx.x * 32;
    const int tid = threadIdx.x;
    const int l   = tid & 63;
    const int w   = tid >> 6;
    const int wm  = w >> 1, wn = w & 1;

    // staging role: thread -> (row, k4) of the 32x32 fp32 A tile
    const int srow = tid >> 3, sk4 = tid & 7;
    const int sfm  = srow >> 4;
    const int slane = (srow & 15) + 16 * (sk4 & 3);
    const int sebase = 4 * (sk4 >> 2);
    const float* aRow = HG ? (A + ((size_t)(m0 + srow) * 12 + h) * 768)
                           : (A + (size_t)(m0 + srow) * 768);

    // B frag pointers: this wave's 2 n-subtiles
    const int nb0 = h * 4 + wn * 2;
    const short* WB = WFm + (size_t)nb0 * 1024 + (size_t)l * 8;

    float4v acc0 = {0.f,0.f,0.f,0.f};
    float4v acc1 = {0.f,0.f,0.f,0.f};

    // prologue: stage k-step 0
    {
        float4 a0 = *(const float4*)(aRow + sk4 * 4);
        S4P hi, lo;
        splitBf(a0.x, hi.s[0], lo.s[0]); splitBf(a0.y, hi.s[1], lo.s[1]);
        splitBf(a0.z, hi.s[2], lo.s[2]); splitBf(a0.w, hi.s[3], lo.s[3]);
        *(int2*)&AF[0][sfm][0][slane][sebase] = hi.i2;
        *(int2*)&AF[0][sfm][1][slane][sebase] = lo.i2;
    }
    // prefetch B for k-step 0
    BP bh0, bl0, bh1, bl1;
    bh0.i4 = *(const int4*)(WB);
    bl0.i4 = *(const int4*)(WB + 512);
    bh1.i4 = *(const int4*)(WB + 1024);
    bl1.i4 = *(const int4*)(WB + 1536);
    __syncthreads();

    #pragma unroll 1
    for (int kt = 0; kt < 24; ++kt){
        const int cur = kt & 1;
        const int ktn = (kt < 23) ? kt + 1 : 23;
        // prefetch next A (regs)
        float4 aN = *(const float4*)(aRow + ktn * 32 + sk4 * 4);
        // current B frags
        BP cbh0 = bh0, cbl0 = bl0, cbh1 = bh1, cbl1 = bl1;
        // prefetch next B
        {
            const short* wb = WB + (size_t)ktn * 49152;
            bh0.i4 = *(const int4*)(wb);
            bl0.i4 = *(const int4*)(wb + 512);
            bh1.i4 = *(const int4*)(wb + 1024);
            bl1.i4 = *(const int4*)(wb + 1536);
        }
        // A frags for this wave
        short8v ah = *(short8v*)&AF[cur][wm][0][l][0];
        short8v al = *(short8v*)&AF[cur][wm][1][l][0];
        acc0 = __builtin_amdgcn_mfma_f32_16x16x32_bf16(ah, cbh0.s8, acc0, 0, 0, 0);
        acc0 = __builtin_amdgcn_mfma_f32_16x16x32_bf16(al, cbh0.s8, acc0, 0, 0, 0);
        acc0 = __builtin_amdgcn_mfma_f32_16x16x32_bf16(ah, cbl0.s8, acc0, 0, 0, 0);
        acc1 = __builtin_amdgcn_mfma_f32_16x16x32_bf16(ah, cbh1.s8, acc1, 0, 0, 0);
        acc1 = __builtin_amdgcn_mfma_f32_16x16x32_bf16(al, cbh1.s8, acc1, 0, 0, 0);
        acc1 = __builtin_amdgcn_mfma_f32_16x16x32_bf16(ah, cbl1.s8, acc1, 0, 0, 0);
        // stage next A into other buffer
        if (kt < 23){
            S4P hi, lo;
            splitBf(aN.x, hi.s[0], lo.s[0]); splitBf(aN.y, hi.s[1], lo.s[1]);
            splitBf(aN.z, hi.s[2], lo.s[2]); splitBf(aN.w, hi.s[3], lo.s[3]);
            *(int2*)&AF[cur ^ 1][sfm][0][slane][sebase] = hi.i2;
            *(int2*)&AF[cur ^ 1][sfm][1][slane][sebase] = lo.i2;
        }
        __syncthreads();
    }

    // epilogue: C/D layout col = l&15, row = (l>>4)*4 + reg
    const int col0 = h * 64 + (wn * 2 + 0) * 16 + (l & 15);
    const int col1 = h * 64 + (wn * 2 + 1) * 16 + (l & 15);
    const float b0 = bias[col0], b1 = bias[col1];
    #pragma unroll
    for (int reg = 0; reg < 4; ++reg){
        int row = m0 + wm * 16 + ((l >> 4) << 2) + reg;
        float v0 = acc0[reg] + b0;
        float v1 = acc1[reg] + b1;
        if (RELU){ v0 = fmaxf(v0, 0.f); v1 = fmaxf(v1, 0.f); }
        C[(size_t)row * 768 + col0] = v0;
        C[(size_t)row * 768 + col1] = v1;
    }
}

// ---------------------------------------------------------------------------
// k_prep: grid 144 = 12 heads x 12 c-tiles. Computes x0 = LN(token),
// qfull0 = x0@Wq0+bq0 (head slice), qbk0[h], qk0T[h][c] = sum_{d in h} Wk0[c,d]*qfull0[d]
// ---------------------------------------------------------------------------
__global__ __launch_bounds__(256) void k_prep(
        const float* __restrict__ token, const float* __restrict__ g1,
        const float* __restrict__ b1,    const float* __restrict__ Wq0,
        const float* __restrict__ bq0,   const float* __restrict__ Wk0,
        const float* __restrict__ bk0,
        float* __restrict__ qk0T, float* __restrict__ qbk0){
    __shared__ float x0l[768];
    __shared__ float red[8];
    __shared__ float qfp[4][64];
    __shared__ float qfl[64];
    __shared__ float Ws[64][68];
    const int h  = blockIdx.x / 12;
    const int ct = blockIdx.x % 12;
    const int tid = threadIdx.x;

    float v0 = token[tid], v1 = token[tid+256], v2 = token[tid+512];
    float s = blockReduce256(v0+v1+v2, red);
    float m = s * (1.f/768.f);
    float d0 = v0-m, d1 = v1-m, d2 = v2-m;
    float qv = blockReduce256(d0*d0+d1*d1+d2*d2, red);
    float rs = rsqrtf(qv*(1.f/768.f) + kEps);
    x0l[tid]     = d0*rs*g1[tid]     + b1[tid];
    x0l[tid+256] = d1*rs*g1[tid+256] + b1[tid+256];
    x0l[tid+512] = d2*rs*g1[tid+512] + b1[tid+512];
    __syncthreads();

    {
        int dl = tid & 63, part = tid >> 6;
        int d = h*64 + dl;
        float a = 0.f;
        for (int c = part*192; c < part*192 + 192; ++c)
            a += x0l[c] * Wq0[(size_t)c*768 + d];
        qfp[part][dl] = a;
    }
    __syncthreads();
    if (tid < 64){
        int d = h*64 + tid;
        qfl[tid] = qfp[0][tid]+qfp[1][tid]+qfp[2][tid]+qfp[3][tid] + bq0[d];
    }
    __syncthreads();
    if (ct == 0 && tid < 64){
        float v = qfl[tid] * bk0[h*64 + tid];
        #pragma unroll
        for (int off = 1; off < 64; off <<= 1) v += __shfl_xor(v, off);
        if (tid == 0) qbk0[h] = v;
    }
    #pragma unroll
    for (int i = 0; i < 4; ++i){
        int f = tid + i*256; int cl = f >> 4, dd = (f & 15)*4;
        float4 v = *(const float4*)(Wk0 + (size_t)(ct*64+cl)*768 + h*64 + dd);
        *(float4*)&Ws[cl][dd] = v;
    }
    __syncthreads();
    {
        int cl = tid >> 2, part = tid & 3;
        float a = 0.f;
        #pragma unroll
        for (int jj = 0; jj < 16; ++jj){
            int dd = part*16 + jj;
            a += Ws[cl][dd] * qfl[dd];
        }
        a += __shfl_xor(a, 1); a += __shfl_xor(a, 2);
        if (part == 0) qk0T[h*768 + ct*64 + cl] = a;
    }
}

// ---------------------------------------------------------------------------
// k_pool: grid 320 (one ROI each). PrRoI pooling (row-skipped) -> P[16][768]
// in LDS -> branch-0 logits/softmax -> s0[r][12][768]
// ---------------------------------------------------------------------------
__global__ __launch_bounds__(256) void k_pool(
        const float* __restrict__ feats, const float* __restrict__ boxes,
        const float* __restrict__ qk0T,  const float* __restrict__ qbk0g,
        float* __restrict__ s0){
    __shared__ float P2[16][776];
    __shared__ float wxp[24][4];
    __shared__ float wyp[24][4];
    __shared__ float logitsL[12][17];
    __shared__ float attnT[16][12];
    __shared__ int   rng[4];
    __shared__ float areaInvS;
    const int r = blockIdx.x, tid = threadIdx.x;

    float bx0 = boxes[r*4+0]*24.f, by0 = boxes[r*4+1]*24.f;
    float bx1 = boxes[r*4+2]*24.f, by1 = boxes[r*4+3]*24.f;
    float bw = (bx1-bx0)*0.25f, bh = (by1-by0)*0.25f;
    if (tid == 0){
        int hlo = (int)floorf(by0) - 1; if (hlo < 0) hlo = 0;
        int hhi = (int)floorf(by1) + 1; if (hhi > 23) hhi = 23;
        int wlo = (int)floorf(bx0) - 1; if (wlo < 0) wlo = 0;
        int whi = (int)floorf(bx1) + 1; if (whi > 23) whi = 23;
        rng[0] = hlo; rng[1] = hhi; rng[2] = wlo >> 2; rng[3] = whi >> 2;
        areaInvS = 1.f / fmaxf(bw*bh, 1e-8f);
    }
    if (tid < 24){
        int w = tid;
        #pragma unroll
        for (int q = 0; q < 4; ++q){
            float e0 = bx0 + q*bw, e1 = e0 + bw;
            wxp[w][q] = Gf(e1 - (float)w) - Gf(e0 - (float)w);
        }
    } else if (tid < 48){
        int hh = tid - 24;
        #pragma unroll
        for (int p = 0; p < 4; ++p){
            float e0 = by0 + p*bh, e1 = e0 + bh;
            wyp[hh][p] = Gf(e1 - (float)hh) - Gf(e0 - (float)hh);
        }
    }
    __syncthreads();
    const int hlo = rng[0], hhi = rng[1], w4lo = rng[2], w4hi = rng[3];
    const float aInv = areaInvS;
    const int j = tid & 7;
    const int cbase = tid >> 3;

    for (int cg = 0; cg < 24; ++cg){
        int c = cg*32 + cbase;
        const float* fb = feats + ((size_t)r*768 + c)*576;
        float acc[16];
        #pragma unroll
        for (int k = 0; k < 16; ++k) acc[k] = 0.f;
        for (int hh = hlo + j; hh <= hhi; hh += 8){
            const float* rowp = fb + hh*24;
            float z[4] = {0.f,0.f,0.f,0.f};
            for (int w4 = w4lo; w4 <= w4hi; ++w4){
                float4 xv = *(const float4*)(rowp + w4*4);
                float xa[4] = {xv.x, xv.y, xv.z, xv.w};
                #pragma unroll
                for (int k = 0; k < 4; ++k){
                    float4 wv = *(const float4*)&wxp[w4*4+k][0];
                    z[0] += wv.x*xa[k]; z[1] += wv.y*xa[k];
                    z[2] += wv.z*xa[k]; z[3] += wv.w*xa[k];
                }
            }
            float4 wyv = *(const float4*)&wyp[hh][0];
            float wya[4] = {wyv.x, wyv.y, wyv.z, wyv.w};
            #pragma unroll
            for (int p = 0; p < 4; ++p)
                #pragma unroll
                for (int q = 0; q < 4; ++q)
                    acc[p*4+q] += wya[p]*z[q];
        }
        #pragma unroll
        for (int k = 0; k < 16; ++k){
            acc[k] += __shfl_xor(acc[k], 1);
            acc[k] += __shfl_xor(acc[k], 2);
            acc[k] += __shfl_xor(acc[k], 4);
        }
        P2[j][c]   = acc[j]   * aInv;
        P2[j+8][c] = acc[j+8] * aInv;
    }
    __syncthreads();

    if (tid < 192){
        int h = tid >> 4, t = tid & 15;
        float a = qbk0g[h];
        const float* qrow = qk0T + h*768;
        #pragma unroll 4
        for (int c4 = 0; c4 < 192; ++c4){
            float4 qv = *(const float4*)(qrow + c4*4);
            float4 pv = *(const float4*)&P2[t][c4*4];
            a += qv.x*pv.x + qv.y*pv.y + qv.z*pv.z + qv.w*pv.w;
        }
        logitsL[h][t] = a * kScale;
    }
    __syncthreads();
    if (tid < 12){
        float mx = -1e30f;
        for (int t = 0; t < 16; ++t) mx = fmaxf(mx, logitsL[tid][t]);
        float ss = 0.f;
        for (int t = 0; t < 16; ++t){
            float e = expf(logitsL[tid][t] - mx);
            attnT[t][tid] = e; ss += e;
        }
        float rsn = 1.f/ss;
        for (int t = 0; t < 16; ++t) attnT[t][tid] *= rsn;
    }
    __syncthreads();
    #pragma unroll
    for (int s3 = 0; s3 < 3; ++s3){
        int c = tid + s3*256;
        float a12[12];
        #pragma unroll
        for (int h = 0; h < 12; ++h) a12[h] = 0.f;
        #pragma unroll
        for (int t = 0; t < 16; ++t){
            float x = P2[t][c];
            float4 a0 = *(const float4*)&attnT[t][0];
            float4 a1 = *(const float4*)&attnT[t][4];
            float4 a2 = *(const float4*)&attnT[t][8];
            a12[0] += a0.x*x; a12[1] += a0.y*x; a12[2]  += a0.z*x; a12[3]  += a0.w*x;
            a12[4] += a1.x*x; a12[5] += a1.y*x; a12[6]  += a1.z*x; a12[7]  += a1.w*x;
            a12[8] += a2.x*x; a12[9] += a2.y*x; a12[10] += a2.z*x; a12[11] += a2.w*x;
        }
        #pragma unroll
        for (int h = 0; h < 12; ++h)
            s0[((size_t)r*12 + h)*768 + c] = a12[h];
    }
}

// ---------------------------------------------------------------------------
// k_qk1: qk1[r][h][c] = sum_{dl<64} qfull1[r, h*64+dl] * Wk1[c, h*64+dl]
// ---------------------------------------------------------------------------
__global__ __launch_bounds__(256) void k_qk1(
        const float* __restrict__ qf1, const float* __restrict__ Wk1,
        float* __restrict__ qk1){
    __shared__ float As[32][68];
    __shared__ float Bs[64][68]; // [d][c]
    const int r0 = blockIdx.x * 32, h = blockIdx.y, c0 = blockIdx.z * 64;
    const int tid = threadIdx.x;
    #pragma unroll
    for (int i = 0; i < 2; ++i){
        int f = tid + i*256; int ml = f >> 4, kk = (f & 15)*4;
        *(float4*)&As[ml][kk] =
            *(const float4*)(qf1 + (size_t)(r0+ml)*768 + h*64 + kk);
    }
    #pragma unroll
    for (int i = 0; i < 4; ++i){
        int f = tid + i*256; int cl = f >> 4, dd = (f & 15)*4;
        float4 v = *(const float4*)(Wk1 + (size_t)(c0+cl)*768 + h*64 + dd);
        Bs[dd+0][cl] = v.x; Bs[dd+1][cl] = v.y;
        Bs[dd+2][cl] = v.z; Bs[dd+3][cl] = v.w;
    }
    __syncthreads();
    const int tn = tid & 15, tm = tid >> 4;
    float acc0[4] = {0.f,0.f,0.f,0.f};
    float acc1[4] = {0.f,0.f,0.f,0.f};
    #pragma unroll
    for (int k4 = 0; k4 < 16; ++k4){
        float4 av0 = *(const float4*)&As[tm*2+0][k4*4];
        float4 av1 = *(const float4*)&As[tm*2+1][k4*4];
        float a0a[4] = {av0.x, av0.y, av0.z, av0.w};
        float a1a[4] = {av1.x, av1.y, av1.z, av1.w};
        #pragma unroll
        for (int jj = 0; jj < 4; ++jj){
            float4 bv = *(const float4*)&Bs[k4*4+jj][tn*4];
            acc0[0] += a0a[jj]*bv.x; acc0[1] += a0a[jj]*bv.y;
            acc0[2] += a0a[jj]*bv.z; acc0[3] += a0a[jj]*bv.w;
            acc1[0] += a1a[jj]*bv.x; acc1[1] += a1a[jj]*bv.y;
            acc1[2] += a1a[jj]*bv.z; acc1[3] += a1a[jj]*bv.w;
        }
    }
    float4 o0; o0.x=acc0[0]; o0.y=acc0[1]; o0.z=acc0[2]; o0.w=acc0[3];
    float4 o1; o1.x=acc1[0]; o1.y=acc1[1]; o1.z=acc1[2]; o1.w=acc1[3];
    *(float4*)(qk1 + ((size_t)(r0+tm*2+0)*12 + h)*768 + c0 + tn*4) = o0;
    *(float4*)(qk1 + ((size_t)(r0+tm*2+1)*12 + h)*768 + c0 + tn*4) = o1;
}

// ---------------------------------------------------------------------------
// k_attn1: grid 320 (one ROI). Branch-1 logits/softmax/s1 against template.
// ---------------------------------------------------------------------------
__global__ __launch_bounds__(256) void k_attn1(
        const float* __restrict__ tmpl, const float* __restrict__ qf1,
        const float* __restrict__ bk1,  const float* __restrict__ qk1,
        float* __restrict__ s1){
    __shared__ float Tc[192][68];
    __shared__ float logitsT[64][13];
    __shared__ float attnH[12][64];
    __shared__ float qbk[12];
    const int r = blockIdx.x, tid = threadIdx.x;
    const float* tp = tmpl + (size_t)r*768*64;

    if (tid < 192){
        int h = tid >> 4, pp = tid & 15;
        float v = 0.f;
        #pragma unroll
        for (int jj = 0; jj < 4; ++jj){
            int d = h*64 + pp*4 + jj;
            v += bk1[d] * qf1[(size_t)r*768 + d];
        }
        v += __shfl_xor(v,1); v += __shfl_xor(v,2);
        v += __shfl_xor(v,4); v += __shfl_xor(v,8);
        if (pp == 0) qbk[h] = v;
    }
    __syncthreads();
    float lacc[3];
    #pragma unroll
    for (int s = 0; s < 3; ++s){
        int task = tid + s*256;
        lacc[s] = qbk[task >> 6];
    }
    for (int cb = 0; cb < 4; ++cb){
        #pragma unroll
        for (int i = 0; i < 12; ++i){
            int f = tid + i*256; int cl = f >> 4, t4 = (f & 15)*4;
            *(float4*)&Tc[cl][t4] =
                *(const float4*)(tp + (size_t)(cb*192 + cl)*64 + t4);
        }
        __syncthreads();
        #pragma unroll
        for (int s = 0; s < 3; ++s){
            int task = tid + s*256;
            int h = task >> 6, t = task & 63;
            const float* qrow = qk1 + ((size_t)r*12 + h)*768 + cb*192;
            float a = 0.f;
            #pragma unroll 4
            for (int c4 = 0; c4 < 48; ++c4){
                float4 qv = *(const float4*)(qrow + c4*4);
                a += qv.x*Tc[c4*4+0][t] + qv.y*Tc[c4*4+1][t]
                   + qv.z*Tc[c4*4+2][t] + qv.w*Tc[c4*4+3][t];
            }
            lacc[s] += a;
        }
        __syncthreads();
    }
    #pragma unroll
    for (int s = 0; s < 3; ++s){
        int task = tid + s*256;
        logitsT[task & 63][task >> 6] = lacc[s] * kScale;
    }
    __syncthreads();
    if (tid < 12){
        float mx = -1e30f;
        for (int t = 0; t < 64; ++t) mx = fmaxf(mx, logitsT[t][tid]);
        float ss = 0.f;
        for (int t = 0; t < 64; ++t){
            float e = expf(logitsT[t][tid] - mx);
            attnH[tid][t] = e; ss += e;
        }
        float rsn = 1.f/ss;
        for (int t = 0; t < 64; ++t) attnH[tid][t] *= rsn;
    }
    __syncthreads();
    for (int cb = 0; cb < 4; ++cb){
        #pragma unroll
        for (int i = 0; i < 12; ++i){
            int f = tid + i*256; int cl = f >> 4, t4 = (f & 15)*4;
            *(float4*)&Tc[cl][t4] =
                *(const float4*)(tp + (size_t)(cb*192 + cl)*64 + t4);
        }
        __syncthreads();
        if (tid < 192){
            float4 trow[16];
            #pragma unroll
            for (int t4 = 0; t4 < 16; ++t4)
                trow[t4] = *(const float4*)&Tc[tid][t4*4];
            int c = cb*192 + tid;
            #pragma unroll
            for (int h = 0; h < 12; ++h){
                float a = 0.f;
                #pragma unroll
                for (int t4 = 0; t4 < 16; ++t4){
                    float4 avv = *(const float4*)&attnH[h][t4*4];
                    float4 tv = trow[t4];
                    a += avv.x*tv.x + avv.y*tv.y + avv.z*tv.z + avv.w*tv.w;
                }
                s1[((size_t)r*12 + h)*768 + c] = a;
            }
        }
        __syncthreads();
    }
}

// ---------------------------------------------------------------------------
// k_lnmix: grid 32 (one b). LN(u[n,b,:]) with ln2 params, then N-mix with Wmix.
// ---------------------------------------------------------------------------
__global__ __launch_bounds__(256) void k_lnmix(
        const float* __restrict__ u, const float* __restrict__ g,
        const float* __restrict__ bta, const float* __restrict__ Wmix,
        const float* __restrict__ bmix, float* __restrict__ xout){
    __shared__ float lnl[10][768];
    __shared__ float red[8];
    __shared__ float wm[100];
    __shared__ float bm[10];
    const int b = blockIdx.x, tid = threadIdx.x;
    if (tid < 100) wm[tid] = Wmix[tid];
    if (tid < 10)  bm[tid] = bmix[tid];
    for (int n = 0; n < 10; ++n){
        const float* row = u + (size_t)(n*32 + b)*768;
        float v0 = row[tid], v1 = row[tid+256], v2 = row[tid+512];
        float s = blockReduce256(v0+v1+v2, red);
        float m = s * (1.f/768.f);
        float d0 = v0-m, d1 = v1-m, d2 = v2-m;
        float qv = blockReduce256(d0*d0+d1*d1+d2*d2, red);
        float rs = rsqrtf(qv*(1.f/768.f) + kEps);
        lnl[n][tid]     = d0*rs*g[tid]     + bta[tid];
        lnl[n][tid+256] = d1*rs*g[tid+256] + bta[tid+256];
        lnl[n][tid+512] = d2*rs*g[tid+512] + bta[tid+512];
    }
    __syncthreads();
    #pragma unroll
    for (int s3 = 0; s3 < 3; ++s3){
        int c = tid + s3*256;
        float col[10];
        #pragma unroll
        for (int n = 0; n < 10; ++n) col[n] = lnl[n][c];
        #pragma unroll
        for (int np = 0; np < 10; ++np){
            float a = bm[np];
            #pragma unroll
            for (int n = 0; n < 10; ++n) a += col[n]*wm[n*10+np];
            xout[(size_t)(np*32 + b)*768 + c] = a;
        }
    }
}

// ---------------------------------------------------------------------------
// k_head: out[r] = b3 + sum_e h2[r][e]*W3[e]
// ---------------------------------------------------------------------------
__global__ __launch_bounds__(256) void k_head(
        const float* __restrict__ h2v, const float* __restrict__ W3,
        const float* __restrict__ b3, float* __restrict__ out){
    __shared__ float red[8];
    const int r = blockIdx.x, tid = threadIdx.x;
    const float* row = h2v + (size_t)r*768;
    float a = row[tid]*W3[tid] + row[tid+256]*W3[tid+256] + row[tid+512]*W3[tid+512];
    a = blockReduce256(a, red);
    if (tid == 0) out[r] = a + b3[0];
}

} // anonymous namespace

extern "C" void kernel_launch(void* const* d_in, const int* in_sizes, int n_in,
                              void* d_out, int out_size, void* d_ws, size_t ws_size,
                              hipStream_t stream){
    const float* feats = (const float*)d_in[0];
    const float* tmpl  = (const float*)d_in[1];
    const float* boxes = (const float*)d_in[2];
    const float* token = (const float*)d_in[3];
    const float* ln1g  = (const float*)d_in[4];
    const float* ln1b  = (const float*)d_in[5];
    const float* Wq    = (const float*)d_in[6];
    const float* bq    = (const float*)d_in[7];
    const float* Wk    = (const float*)d_in[8];
    const float* bk    = (const float*)d_in[9];
    const float* Wv    = (const float*)d_in[10];
    const float* bv    = (const float*)d_in[11];
    const float* Wo    = (const float*)d_in[12];
    const float* bo    = (const float*)d_in[13];
    const float* ln2g  = (const float*)d_in[14];
    const float* ln2b  = (const float*)d_in[15];
    const float* Wmix  = (const float*)d_in[16];
    const float* bmix  = (const float*)d_in[17];
    const float* W1    = (const float*)d_in[18];
    const float* b1v   = (const float*)d_in[19];
    const float* W2    = (const float*)d_in[20];
    const float* b2v   = (const float*)d_in[21];
    const float* W3    = (const float*)d_in[22];
    const float* b3v   = (const float*)d_in[23];
    float* ws  = (float*)d_ws;
    float* out = (float*)d_out;

    float* qk0T = ws + OFF_QK0T;
    float* qbk0 = ws + OFF_QBK0;
    float* sbuf = ws + OFF_S;
    float* qk1  = ws + OFF_QK1;
    float* obuf = ws + OFF_O;
    float* ubuf = ws + OFF_U;
    float* xbuf = ws + OFF_X;
    float* qf1  = ws + OFF_QF1;
    float* h1b  = ws + OFF_H1;
    float* h2b  = ws + OFF_H2;
    short* wf   = (short*)(ws + OFF_WF);

    const size_t MO = 589824; // 768*768
    // frag-weight order: 0:Wv0 1:Wo0 2:Wq1 3:Wv1 4:Wo1 5:W1 6:W2
    short* wfv0 = wf + 0*WF_MAT_SHORTS;
    short* wfo0 = wf + 1*WF_MAT_SHORTS;
    short* wfq1 = wf + 2*WF_MAT_SHORTS;
    short* wfv1 = wf + 3*WF_MAT_SHORTS;
    short* wfo1 = wf + 4*WF_MAT_SHORTS;
    short* wf1  = wf + 5*WF_MAT_SHORTS;
    short* wf2  = wf + 6*WF_MAT_SHORTS;

    k_wprep<<<dim3(288,7), 256, 0, stream>>>(Wv, Wo, Wq + MO, Wv + MO, Wo + MO, W1, W2, wf);
    k_prep<<<144, 256, 0, stream>>>(token, ln1g, ln1b, Wq, bq, Wk, bk, qk0T, qbk0);
    k_pool<<<320, 256, 0, stream>>>(feats, boxes, qk0T, qbk0, sbuf);
    k_mgemm<1,0><<<dim3(10,12), 256, 0, stream>>>(sbuf, wfv0, bv, obuf);
    k_mgemm<0,0><<<dim3(10,12), 256, 0, stream>>>(obuf, wfo0, bo, ubuf);
    k_lnmix<<<32, 256, 0, stream>>>(ubuf, ln2g, ln2b, Wmix, bmix, xbuf);
    k_mgemm<0,0><<<dim3(10,12), 256, 0, stream>>>(xbuf, wfq1, bq + 768, qf1);
    k_qk1<<<dim3(10,12,12), 256, 0, stream>>>(qf1, Wk + MO, qk1);
    k_attn1<<<320, 256, 0, stream>>>(tmpl, qf1, bk + 768, qk1, sbuf);
    k_mgemm<1,0><<<dim3(10,12), 256, 0, stream>>>(sbuf, wfv1, bv + 768, obuf);
    k_mgemm<0,0><<<dim3(10,12), 256, 0, stream>>>(obuf, wfo1, bo + 768, ubuf);
    k_lnmix<<<32, 256, 0, stream>>>(ubuf, ln2g + 768, ln2b + 768, Wmix + 100, bmix + 10, xbuf);
    k_mgemm<0,1><<<dim3(10,12), 256, 0, stream>>>(xbuf, wf1, b1v, h1b);
    k_mgemm<0,1><<<dim3(10,12), 256, 0, stream>>>(h1b, wf2, b2v, h2b);
    k_head<<<320, 256, 0, stream>>>(h2b, W3, b3v, out);
}

// Round 3
// 404.260 us; speedup vs baseline: 1.0503x; 1.0503x over previous
//
#include <hip/hip_runtime.h>
#include <cstdint>
#include <cstddef>

namespace {

constexpr float kScale = 0.03608439182435161f; // 768^-0.5
constexpr float kEps   = 1e-5f;

// workspace offsets (in floats)
constexpr size_t OFF_QK0T = 0;                       // 12*768
constexpr size_t OFF_QBK0 = 9216;                    // 12
constexpr size_t OFF_S    = 16384;                   // 320*12*768 (s0, later s1)
constexpr size_t OFF_QK1  = OFF_S   + 2949120;       // 320*12*768
constexpr size_t OFF_O    = OFF_QK1 + 2949120;       // 320*768
constexpr size_t OFF_U    = OFF_O   + 245760;
constexpr size_t OFF_X    = OFF_U   + 245760;
constexpr size_t OFF_QF1  = OFF_X   + 245760;
constexpr size_t OFF_H1   = OFF_QF1 + 245760;
constexpr size_t OFF_H2   = OFF_H1  + 245760;
constexpr size_t OFF_WF   = OFF_H2  + 245760;        // bf16 frag weights (shorts)
constexpr size_t WF_MAT_SHORTS = 1179648;            // 24*48*2*64*8
constexpr size_t OFF_P    = OFF_WF + (7*WF_MAT_SHORTS)/2; // P[320][16][768]

typedef short short8v __attribute__((ext_vector_type(8)));
typedef float float4v __attribute__((ext_vector_type(4)));

union BP  { int4 i4; short8v s8; };
union S4P { int2 i2; short s[4]; };

__device__ __forceinline__ void splitBf(float a, short &h, short &l){
    unsigned u = __float_as_uint(a);
    h = (short)(u >> 16);
    float r = a - __uint_as_float(u & 0xFFFF0000u);
    l = (short)(__float_as_uint(r) >> 16);
}

__device__ __forceinline__ float Gf(float t){
    float tc = fminf(fmaxf(t, -1.f), 1.f);
    return 0.5f + tc * (1.f - 0.5f * fabsf(tc));
}

__device__ __forceinline__ float blockReduce256(float v, float* red){
    #pragma unroll
    for (int off = 1; off < 64; off <<= 1) v += __shfl_xor(v, off);
    __syncthreads();
    if ((threadIdx.x & 63) == 0) red[threadIdx.x >> 6] = v;
    __syncthreads();
    return red[0] + red[1] + red[2] + red[3];
}

// ---------------------------------------------------------------------------
// k_wprep: convert 7 weight matrices (768x768 fp32, row-major [k][n]) into
// MFMA fragment-ordered bf16 hi/lo: WF[mat][kt(24)][nb(48)][hl(2)][lane(64)][e(8)]
// frag mapping (16x16x32 bf16): k = kt*32 + (l>>4)*4 + (e&3) + 16*(e>>2),
//                               n = nb*16 + (l&15)
// ---------------------------------------------------------------------------
__global__ __launch_bounds__(256) void k_wprep(
        const float* __restrict__ w0, const float* __restrict__ w1,
        const float* __restrict__ w2, const float* __restrict__ w3,
        const float* __restrict__ w4, const float* __restrict__ w5,
        const float* __restrict__ w6, short* __restrict__ WF){
    const float* Wsel[7] = {w0,w1,w2,w3,w4,w5,w6};
    const float* W = Wsel[blockIdx.y];
    const int unit = blockIdx.x * 4 + (threadIdx.x >> 6); // 0..1151
    const int l = threadIdx.x & 63;
    const int kt = unit / 48, nb = unit % 48;
    const int n = nb*16 + (l & 15);
    const int kb = kt*32 + ((l >> 4) << 2);
    S4P hi0, hi1, lo0, lo1;
    #pragma unroll
    for (int e = 0; e < 4; ++e){
        float a = W[(size_t)(kb + e) * 768 + n];
        splitBf(a, hi0.s[e], lo0.s[e]);
        float b = W[(size_t)(kb + 16 + e) * 768 + n];
        splitBf(b, hi1.s[e], lo1.s[e]);
    }
    size_t base = (size_t)blockIdx.y * WF_MAT_SHORTS + (size_t)unit * 1024 + (size_t)l * 8;
    *(int2*)(WF + base)            = hi0.i2;
    *(int2*)(WF + base + 4)        = hi1.i2;
    *(int2*)(WF + base + 512)      = lo0.i2;
    *(int2*)(WF + base + 512 + 4)  = lo1.i2;
}

// ---------------------------------------------------------------------------
// k_mgemm: C[m][n] = act(bias[n] + A[320x768] @ W[768x768]) via bf16 hi/lo MFMA
// grid (20, 12): 16x64 tile, 4 waves, wave w owns nb = h*4+w. K-step 32.
// HG: A row = (m*12 + blockIdx.y)*768 (head-gathered s buffer).
// ---------------------------------------------------------------------------
template<int HG, int RELU>
__global__ __launch_bounds__(256) void k_mgemm(
        const float* __restrict__ A, const short* __restrict__ WFm,
        const float* __restrict__ bias, float* __restrict__ C){
    __shared__ short AF[2][2][64][8]; // [buf][hl][lane][e]
    const int h   = blockIdx.y;
    const int m0  = blockIdx.x * 16;
    const int tid = threadIdx.x;
    const int l   = tid & 63;
    const int w   = tid >> 6;

    // staging role (tid<128): thread -> (row, k4) of the 16x32 fp32 A tile
    const int srow = tid >> 3, sk4 = tid & 7;
    const int slane = srow + 16 * (sk4 & 3);
    const int sebase = 4 * (sk4 >> 2);
    const float* aRow = HG ? (A + ((size_t)(m0 + srow) * 12 + h) * 768)
                           : (A + (size_t)(m0 + srow) * 768);

    const int nb = h * 4 + w;
    const short* WB = WFm + (size_t)nb * 1024 + (size_t)l * 8;

    float4v acc = {0.f,0.f,0.f,0.f};

    if (tid < 128){
        float4 a0 = *(const float4*)(aRow + sk4 * 4);
        S4P hi, lo;
        splitBf(a0.x, hi.s[0], lo.s[0]); splitBf(a0.y, hi.s[1], lo.s[1]);
        splitBf(a0.z, hi.s[2], lo.s[2]); splitBf(a0.w, hi.s[3], lo.s[3]);
        *(int2*)&AF[0][0][slane][sebase] = hi.i2;
        *(int2*)&AF[0][1][slane][sebase] = lo.i2;
    }
    BP bh, bl;
    bh.i4 = *(const int4*)(WB);
    bl.i4 = *(const int4*)(WB + 512);
    __syncthreads();

    #pragma unroll 1
    for (int kt = 0; kt < 24; ++kt){
        const int cur = kt & 1;
        const int ktn = (kt < 23) ? kt + 1 : 23;
        float4 aN;
        if (tid < 128) aN = *(const float4*)(aRow + ktn * 32 + sk4 * 4);
        BP cbh = bh, cbl = bl;
        {
            const short* wb = WB + (size_t)ktn * 49152;
            bh.i4 = *(const int4*)(wb);
            bl.i4 = *(const int4*)(wb + 512);
        }
        short8v ah = *(short8v*)&AF[cur][0][l][0];
        short8v al = *(short8v*)&AF[cur][1][l][0];
        acc = __builtin_amdgcn_mfma_f32_16x16x32_bf16(ah, cbh.s8, acc, 0, 0, 0);
        acc = __builtin_amdgcn_mfma_f32_16x16x32_bf16(al, cbh.s8, acc, 0, 0, 0);
        acc = __builtin_amdgcn_mfma_f32_16x16x32_bf16(ah, cbl.s8, acc, 0, 0, 0);
        if (kt < 23 && tid < 128){
            S4P hi, lo;
            splitBf(aN.x, hi.s[0], lo.s[0]); splitBf(aN.y, hi.s[1], lo.s[1]);
            splitBf(aN.z, hi.s[2], lo.s[2]); splitBf(aN.w, hi.s[3], lo.s[3]);
            *(int2*)&AF[cur ^ 1][0][slane][sebase] = hi.i2;
            *(int2*)&AF[cur ^ 1][1][slane][sebase] = lo.i2;
        }
        __syncthreads();
    }

    const int col = h * 64 + w * 16 + (l & 15);
    const float bb = bias[col];
    #pragma unroll
    for (int reg = 0; reg < 4; ++reg){
        int row = m0 + ((l >> 4) << 2) + reg;
        float v = acc[reg] + bb;
        if (RELU) v = fmaxf(v, 0.f);
        C[(size_t)row * 768 + col] = v;
    }
}

// ---------------------------------------------------------------------------
// k_prep: grid 144 = 12 heads x 12 c-tiles. x0=LN(token), qfull0, qbk0, qk0T.
// ---------------------------------------------------------------------------
__global__ __launch_bounds__(256) void k_prep(
        const float* __restrict__ token, const float* __restrict__ g1,
        const float* __restrict__ b1,    const float* __restrict__ Wq0,
        const float* __restrict__ bq0,   const float* __restrict__ Wk0,
        const float* __restrict__ bk0,
        float* __restrict__ qk0T, float* __restrict__ qbk0){
    __shared__ float x0l[768];
    __shared__ float red[8];
    __shared__ float qfp[4][64];
    __shared__ float qfl[64];
    __shared__ float Ws[64][68];
    const int h  = blockIdx.x / 12;
    const int ct = blockIdx.x % 12;
    const int tid = threadIdx.x;

    float v0 = token[tid], v1 = token[tid+256], v2 = token[tid+512];
    float s = blockReduce256(v0+v1+v2, red);
    float m = s * (1.f/768.f);
    float d0 = v0-m, d1 = v1-m, d2 = v2-m;
    float qv = blockReduce256(d0*d0+d1*d1+d2*d2, red);
    float rs = rsqrtf(qv*(1.f/768.f) + kEps);
    x0l[tid]     = d0*rs*g1[tid]     + b1[tid];
    x0l[tid+256] = d1*rs*g1[tid+256] + b1[tid+256];
    x0l[tid+512] = d2*rs*g1[tid+512] + b1[tid+512];
    __syncthreads();

    {
        int dl = tid & 63, part = tid >> 6;
        int d = h*64 + dl;
        float a = 0.f;
        for (int c = part*192; c < part*192 + 192; ++c)
            a += x0l[c] * Wq0[(size_t)c*768 + d];
        qfp[part][dl] = a;
    }
    __syncthreads();
    if (tid < 64){
        int d = h*64 + tid;
        qfl[tid] = qfp[0][tid]+qfp[1][tid]+qfp[2][tid]+qfp[3][tid] + bq0[d];
    }
    __syncthreads();
    if (ct == 0 && tid < 64){
        float v = qfl[tid] * bk0[h*64 + tid];
        #pragma unroll
        for (int off = 1; off < 64; off <<= 1) v += __shfl_xor(v, off);
        if (tid == 0) qbk0[h] = v;
    }
    #pragma unroll
    for (int i = 0; i < 4; ++i){
        int f = tid + i*256; int cl = f >> 4, dd = (f & 15)*4;
        float4 v = *(const float4*)(Wk0 + (size_t)(ct*64+cl)*768 + h*64 + dd);
        *(float4*)&Ws[cl][dd] = v;
    }
    __syncthreads();
    {
        int cl = tid >> 2, part = tid & 3;
        float a = 0.f;
        #pragma unroll
        for (int jj = 0; jj < 16; ++jj){
            int dd = part*16 + jj;
            a += Ws[cl][dd] * qfl[dd];
        }
        a += __shfl_xor(a, 1); a += __shfl_xor(a, 2);
        if (part == 0) qk0T[h*768 + ct*64 + cl] = a;
    }
}

// ---------------------------------------------------------------------------
// k_pool2: grid (320, 24). One ROI x 32 channels per block. Coalesced
// row-skipped staging of feats rows into LDS, then PrRoI pooling ->
// P[r][t][c] (t = p*4+q).
// ---------------------------------------------------------------------------
__global__ __launch_bounds__(256) void k_pool2(
        const float* __restrict__ feats, const float* __restrict__ boxes,
        float* __restrict__ P){
    __shared__ float Xs[32*580];   // [c][24 rows][24 w] with 580-stride per c
    __shared__ float wxp[24][4];
    __shared__ float wyp[24][4];
    __shared__ int   rng[2];
    __shared__ float areaInvS;
    const int r = blockIdx.x, cc = blockIdx.y * 32, tid = threadIdx.x;

    float bx0 = boxes[r*4+0]*24.f, by0 = boxes[r*4+1]*24.f;
    float bx1 = boxes[r*4+2]*24.f, by1 = boxes[r*4+3]*24.f;
    float bw = (bx1-bx0)*0.25f, bh = (by1-by0)*0.25f;
    if (tid == 0){
        int hlo = (int)floorf(by0) - 1; if (hlo < 0) hlo = 0;
        int hhi = (int)floorf(by1) + 1; if (hhi > 23) hhi = 23;
        rng[0] = hlo; rng[1] = hhi - hlo + 1;
        areaInvS = 1.f / fmaxf(bw*bh, 1e-8f);
    }
    if (tid < 24){
        int w = tid;
        #pragma unroll
        for (int q = 0; q < 4; ++q){
            float e0 = bx0 + q*bw, e1 = e0 + bw;
            wxp[w][q] = Gf(e1 - (float)w) - Gf(e0 - (float)w);
        }
    } else if (tid < 48){
        int hh = tid - 24;
        #pragma unroll
        for (int p = 0; p < 4; ++p){
            float e0 = by0 + p*bh, e1 = e0 + bh;
            wyp[hh][p] = Gf(e1 - (float)hh) - Gf(e0 - (float)hh);
        }
    }
    __syncthreads();
    const int hlo = rng[0], nr = rng[1];
    const float aInv = areaInvS;

    // stage: nr*192 float4 loads, coalesced in (c-row segments of 96B)
    const int nf4 = nr * 192;
    for (int idx = tid; idx < nf4; idx += 256){
        int ri  = idx / 192;
        int rem = idx - ri * 192;
        int cl  = rem / 6;
        int w4  = rem - cl * 6;
        float4 v = *(const float4*)(feats + ((size_t)(r*768 + cc + cl))*576
                                    + (hlo + ri)*24 + w4*4);
        *(float4*)&Xs[cl*580 + ri*24 + w4*4] = v;
    }
    __syncthreads();

    // compute: thread (j = tid&7 row-lane, cl = tid>>3 channel)
    const int j = tid & 7;
    const int cl = tid >> 3;
    float acc[16];
    #pragma unroll
    for (int k = 0; k < 16; ++k) acc[k] = 0.f;
    for (int ri = j; ri < nr; ri += 8){
        const float* xr = &Xs[cl*580 + ri*24];
        float z[4] = {0.f,0.f,0.f,0.f};
        #pragma unroll
        for (int w4 = 0; w4 < 6; ++w4){
            float4 xv = *(const float4*)(xr + w4*4);
            float xa[4] = {xv.x, xv.y, xv.z, xv.w};
            #pragma unroll
            for (int k = 0; k < 4; ++k){
                float4 wv = *(const float4*)&wxp[w4*4+k][0];
                z[0] += wv.x*xa[k]; z[1] += wv.y*xa[k];
                z[2] += wv.z*xa[k]; z[3] += wv.w*xa[k];
            }
        }
        float4 wyv = *(const float4*)&wyp[hlo+ri][0];
        float wya[4] = {wyv.x, wyv.y, wyv.z, wyv.w};
        #pragma unroll
        for (int p = 0; p < 4; ++p)
            #pragma unroll
            for (int q = 0; q < 4; ++q)
                acc[p*4+q] += wya[p]*z[q];
    }
    #pragma unroll
    for (int k = 0; k < 16; ++k){
        acc[k] += __shfl_xor(acc[k], 1);
        acc[k] += __shfl_xor(acc[k], 2);
        acc[k] += __shfl_xor(acc[k], 4);
    }
    // static-index select of acc[j], acc[j+8] (avoid scratch)
    float o0 = acc[0], o1 = acc[8];
    #pragma unroll
    for (int k = 1; k < 8; ++k){
        if (j == k){ o0 = acc[k]; o1 = acc[k+8]; }
    }
    P[((size_t)r*16 + j)*768 + cc + cl]     = o0 * aInv;
    P[((size_t)r*16 + j + 8)*768 + cc + cl] = o1 * aInv;
}

// ---------------------------------------------------------------------------
// k_attn0: grid 320. Stage P[r] (16x768), branch-0 logits/softmax -> s0.
// ---------------------------------------------------------------------------
__global__ __launch_bounds__(256) void k_attn0(
        const float* __restrict__ P, const float* __restrict__ qk0T,
        const float* __restrict__ qbk0g, float* __restrict__ s0){
    __shared__ float P2[16][776];
    __shared__ float logitsL[12][17];
    __shared__ float attnT[16][12];
    const int r = blockIdx.x, tid = threadIdx.x;

    #pragma unroll
    for (int i = 0; i < 12; ++i){
        int f = tid + i*256;
        int t = f / 192, c4 = f - t*192;
        float4 v = *(const float4*)(P + ((size_t)r*16 + t)*768 + c4*4);
        *(float4*)&P2[t][c4*4] = v;
    }
    __syncthreads();

    if (tid < 192){
        int h = tid >> 4, t = tid & 15;
        float a = qbk0g[h];
        const float* qrow = qk0T + h*768;
        #pragma unroll 4
        for (int c4 = 0; c4 < 192; ++c4){
            float4 qv = *(const float4*)(qrow + c4*4);
            float4 pv = *(const float4*)&P2[t][c4*4];
            a += qv.x*pv.x + qv.y*pv.y + qv.z*pv.z + qv.w*pv.w;
        }
        logitsL[h][t] = a * kScale;
    }
    __syncthreads();
    if (tid < 12){
        float mx = -1e30f;
        for (int t = 0; t < 16; ++t) mx = fmaxf(mx, logitsL[tid][t]);
        float ss = 0.f;
        for (int t = 0; t < 16; ++t){
            float e = expf(logitsL[tid][t] - mx);
            attnT[t][tid] = e; ss += e;
        }
        float rsn = 1.f/ss;
        for (int t = 0; t < 16; ++t) attnT[t][tid] *= rsn;
    }
    __syncthreads();
    #pragma unroll
    for (int s3 = 0; s3 < 3; ++s3){
        int c = tid + s3*256;
        float a12[12];
        #pragma unroll
        for (int h = 0; h < 12; ++h) a12[h] = 0.f;
        #pragma unroll
        for (int t = 0; t < 16; ++t){
            float x = P2[t][c];
            float4 a0 = *(const float4*)&attnT[t][0];
            float4 a1 = *(const float4*)&attnT[t][4];
            float4 a2 = *(const float4*)&attnT[t][8];
            a12[0] += a0.x*x; a12[1] += a0.y*x; a12[2]  += a0.z*x; a12[3]  += a0.w*x;
            a12[4] += a1.x*x; a12[5] += a1.y*x; a12[6]  += a1.z*x; a12[7]  += a1.w*x;
            a12[8] += a2.x*x; a12[9] += a2.y*x; a12[10] += a2.z*x; a12[11] += a2.w*x;
        }
        #pragma unroll
        for (int h = 0; h < 12; ++h)
            s0[((size_t)r*12 + h)*768 + c] = a12[h];
    }
}

// ---------------------------------------------------------------------------
// k_qk1: qk1[r][h][c] = sum_{dl<64} qfull1[r, h*64+dl] * Wk1[c, h*64+dl]
// ---------------------------------------------------------------------------
__global__ __launch_bounds__(256) void k_qk1(
        const float* __restrict__ qf1, const float* __restrict__ Wk1,
        float* __restrict__ qk1){
    __shared__ float As[32][68];
    __shared__ float Bs[64][68]; // [d][c]
    const int r0 = blockIdx.x * 32, h = blockIdx.y, c0 = blockIdx.z * 64;
    const int tid = threadIdx.x;
    #pragma unroll
    for (int i = 0; i < 2; ++i){
        int f = tid + i*256; int ml = f >> 4, kk = (f & 15)*4;
        *(float4*)&As[ml][kk] =
            *(const float4*)(qf1 + (size_t)(r0+ml)*768 + h*64 + kk);
    }
    #pragma unroll
    for (int i = 0; i < 4; ++i){
        int f = tid + i*256; int cl = f >> 4, dd = (f & 15)*4;
        float4 v = *(const float4*)(Wk1 + (size_t)(c0+cl)*768 + h*64 + dd);
        Bs[dd+0][cl] = v.x; Bs[dd+1][cl] = v.y;
        Bs[dd+2][cl] = v.z; Bs[dd+3][cl] = v.w;
    }
    __syncthreads();
    const int tn = tid & 15, tm = tid >> 4;
    float acc0[4] = {0.f,0.f,0.f,0.f};
    float acc1[4] = {0.f,0.f,0.f,0.f};
    #pragma unroll
    for (int k4 = 0; k4 < 16; ++k4){
        float4 av0 = *(const float4*)&As[tm*2+0][k4*4];
        float4 av1 = *(const float4*)&As[tm*2+1][k4*4];
        float a0a[4] = {av0.x, av0.y, av0.z, av0.w};
        float a1a[4] = {av1.x, av1.y, av1.z, av1.w};
        #pragma unroll
        for (int jj = 0; jj < 4; ++jj){
            float4 bv = *(const float4*)&Bs[k4*4+jj][tn*4];
            acc0[0] += a0a[jj]*bv.x; acc0[1] += a0a[jj]*bv.y;
            acc0[2] += a0a[jj]*bv.z; acc0[3] += a0a[jj]*bv.w;
            acc1[0] += a1a[jj]*bv.x; acc1[1] += a1a[jj]*bv.y;
            acc1[2] += a1a[jj]*bv.z; acc1[3] += a1a[jj]*bv.w;
        }
    }
    float4 o0; o0.x=acc0[0]; o0.y=acc0[1]; o0.z=acc0[2]; o0.w=acc0[3];
    float4 o1; o1.x=acc1[0]; o1.y=acc1[1]; o1.z=acc1[2]; o1.w=acc1[3];
    *(float4*)(qk1 + ((size_t)(r0+tm*2+0)*12 + h)*768 + c0 + tn*4) = o0;
    *(float4*)(qk1 + ((size_t)(r0+tm*2+1)*12 + h)*768 + c0 + tn*4) = o1;
}

// ---------------------------------------------------------------------------
// k_attn1: grid 320 (one ROI). Branch-1 logits/softmax/s1 against template.
// ---------------------------------------------------------------------------
__global__ __launch_bounds__(256) void k_attn1(
        const float* __restrict__ tmpl, const float* __restrict__ qf1,
        const float* __restrict__ bk1,  const float* __restrict__ qk1,
        float* __restrict__ s1){
    __shared__ float Tc[192][68];
    __shared__ float logitsT[64][13];
    __shared__ float attnH[12][64];
    __shared__ float qbk[12];
    const int r = blockIdx.x, tid = threadIdx.x;
    const float* tp = tmpl + (size_t)r*768*64;

    if (tid < 192){
        int h = tid >> 4, pp = tid & 15;
        float v = 0.f;
        #pragma unroll
        for (int jj = 0; jj < 4; ++jj){
            int d = h*64 + pp*4 + jj;
            v += bk1[d] * qf1[(size_t)r*768 + d];
        }
        v += __shfl_xor(v,1); v += __shfl_xor(v,2);
        v += __shfl_xor(v,4); v += __shfl_xor(v,8);
        if (pp == 0) qbk[h] = v;
    }
    __syncthreads();
    float lacc[3];
    #pragma unroll
    for (int s = 0; s < 3; ++s){
        int task = tid + s*256;
        lacc[s] = qbk[task >> 6];
    }
    for (int cb = 0; cb < 4; ++cb){
        #pragma unroll
        for (int i = 0; i < 12; ++i){
            int f = tid + i*256; int cl = f >> 4, t4 = (f & 15)*4;
            *(float4*)&Tc[cl][t4] =
                *(const float4*)(tp + (size_t)(cb*192 + cl)*64 + t4);
        }
        __syncthreads();
        #pragma unroll
        for (int s = 0; s < 3; ++s){
            int task = tid + s*256;
            int h = task >> 6, t = task & 63;
            const float* qrow = qk1 + ((size_t)r*12 + h)*768 + cb*192;
            float a = 0.f;
            #pragma unroll 4
            for (int c4 = 0; c4 < 48; ++c4){
                float4 qv = *(const float4*)(qrow + c4*4);
                a += qv.x*Tc[c4*4+0][t] + qv.y*Tc[c4*4+1][t]
                   + qv.z*Tc[c4*4+2][t] + qv.w*Tc[c4*4+3][t];
            }
            lacc[s] += a;
        }
        __syncthreads();
    }
    #pragma unroll
    for (int s = 0; s < 3; ++s){
        int task = tid + s*256;
        logitsT[task & 63][task >> 6] = lacc[s] * kScale;
    }
    __syncthreads();
    if (tid < 12){
        float mx = -1e30f;
        for (int t = 0; t < 64; ++t) mx = fmaxf(mx, logitsT[t][tid]);
        float ss = 0.f;
        for (int t = 0; t < 64; ++t){
            float e = expf(logitsT[t][tid] - mx);
            attnH[tid][t] = e; ss += e;
        }
        float rsn = 1.f/ss;
        for (int t = 0; t < 64; ++t) attnH[tid][t] *= rsn;
    }
    __syncthreads();
    for (int cb = 0; cb < 4; ++cb){
        #pragma unroll
        for (int i = 0; i < 12; ++i){
            int f = tid + i*256; int cl = f >> 4, t4 = (f & 15)*4;
            *(float4*)&Tc[cl][t4] =
                *(const float4*)(tp + (size_t)(cb*192 + cl)*64 + t4);
        }
        __syncthreads();
        if (tid < 192){
            float4 trow[16];
            #pragma unroll
            for (int t4 = 0; t4 < 16; ++t4)
                trow[t4] = *(const float4*)&Tc[tid][t4*4];
            int c = cb*192 + tid;
            #pragma unroll
            for (int h = 0; h < 12; ++h){
                float a = 0.f;
                #pragma unroll
                for (int t4 = 0; t4 < 16; ++t4){
                    float4 avv = *(const float4*)&attnH[h][t4*4];
                    float4 tv = trow[t4];
                    a += avv.x*tv.x + avv.y*tv.y + avv.z*tv.z + avv.w*tv.w;
                }
                s1[((size_t)r*12 + h)*768 + c] = a;
            }
        }
        __syncthreads();
    }
}

// ---------------------------------------------------------------------------
// k_lnmix: grid 32 (one b). LN(u[n,b,:]) with ln2 params, then N-mix with Wmix.
// ---------------------------------------------------------------------------
__global__ __launch_bounds__(256) void k_lnmix(
        const float* __restrict__ u, const float* __restrict__ g,
        const float* __restrict__ bta, const float* __restrict__ Wmix,
        const float* __restrict__ bmix, float* __restrict__ xout){
    __shared__ float lnl[10][768];
    __shared__ float red[8];
    __shared__ float wm[100];
    __shared__ float bm[10];
    const int b = blockIdx.x, tid = threadIdx.x;
    if (tid < 100) wm[tid] = Wmix[tid];
    if (tid < 10)  bm[tid] = bmix[tid];
    for (int n = 0; n < 10; ++n){
        const float* row = u + (size_t)(n*32 + b)*768;
        float v0 = row[tid], v1 = row[tid+256], v2 = row[tid+512];
        float s = blockReduce256(v0+v1+v2, red);
        float m = s * (1.f/768.f);
        float d0 = v0-m, d1 = v1-m, d2 = v2-m;
        float qv = blockReduce256(d0*d0+d1*d1+d2*d2, red);
        float rs = rsqrtf(qv*(1.f/768.f) + kEps);
        lnl[n][tid]     = d0*rs*g[tid]     + bta[tid];
        lnl[n][tid+256] = d1*rs*g[tid+256] + bta[tid+256];
        lnl[n][tid+512] = d2*rs*g[tid+512] + bta[tid+512];
    }
    __syncthreads();
    #pragma unroll
    for (int s3 = 0; s3 < 3; ++s3){
        int c = tid + s3*256;
        float col[10];
        #pragma unroll
        for (int n = 0; n < 10; ++n) col[n] = lnl[n][c];
        #pragma unroll
        for (int np = 0; np < 10; ++np){
            float a = bm[np];
            #pragma unroll
            for (int n = 0; n < 10; ++n) a += col[n]*wm[n*10+np];
            xout[(size_t)(np*32 + b)*768 + c] = a;
        }
    }
}

// ---------------------------------------------------------------------------
// k_head: out[r] = b3 + sum_e h2[r][e]*W3[e]
// ---------------------------------------------------------------------------
__global__ __launch_bounds__(256) void k_head(
        const float* __restrict__ h2v, const float* __restrict__ W3,
        const float* __restrict__ b3, float* __restrict__ out){
    __shared__ float red[8];
    const int r = blockIdx.x, tid = threadIdx.x;
    const float* row = h2v + (size_t)r*768;
    float a = row[tid]*W3[tid] + row[tid+256]*W3[tid+256] + row[tid+512]*W3[tid+512];
    a = blockReduce256(a, red);
    if (tid == 0) out[r] = a + b3[0];
}

} // anonymous namespace

extern "C" void kernel_launch(void* const* d_in, const int* in_sizes, int n_in,
                              void* d_out, int out_size, void* d_ws, size_t ws_size,
                              hipStream_t stream){
    const float* feats = (const float*)d_in[0];
    const float* tmpl  = (const float*)d_in[1];
    const float* boxes = (const float*)d_in[2];
    const float* token = (const float*)d_in[3];
    const float* ln1g  = (const float*)d_in[4];
    const float* ln1b  = (const float*)d_in[5];
    const float* Wq    = (const float*)d_in[6];
    const float* bq    = (const float*)d_in[7];
    const float* Wk    = (const float*)d_in[8];
    const float* bk    = (const float*)d_in[9];
    const float* Wv    = (const float*)d_in[10];
    const float* bv    = (const float*)d_in[11];
    const float* Wo    = (const float*)d_in[12];
    const float* bo    = (const float*)d_in[13];
    const float* ln2g  = (const float*)d_in[14];
    const float* ln2b  = (const float*)d_in[15];
    const float* Wmix  = (const float*)d_in[16];
    const float* bmix  = (const float*)d_in[17];
    const float* W1    = (const float*)d_in[18];
    const float* b1v   = (const float*)d_in[19];
    const float* W2    = (const float*)d_in[20];
    const float* b2v   = (const float*)d_in[21];
    const float* W3    = (const float*)d_in[22];
    const float* b3v   = (const float*)d_in[23];
    float* ws  = (float*)d_ws;
    float* out = (float*)d_out;

    float* qk0T = ws + OFF_QK0T;
    float* qbk0 = ws + OFF_QBK0;
    float* sbuf = ws + OFF_S;
    float* qk1  = ws + OFF_QK1;
    float* obuf = ws + OFF_O;
    float* ubuf = ws + OFF_U;
    float* xbuf = ws + OFF_X;
    float* qf1  = ws + OFF_QF1;
    float* h1b  = ws + OFF_H1;
    float* h2b  = ws + OFF_H2;
    short* wf   = (short*)(ws + OFF_WF);
    float* Pbuf = ws + OFF_P;

    const size_t MO = 589824; // 768*768
    // frag-weight order: 0:Wv0 1:Wo0 2:Wq1 3:Wv1 4:Wo1 5:W1 6:W2
    short* wfv0 = wf + 0*WF_MAT_SHORTS;
    short* wfo0 = wf + 1*WF_MAT_SHORTS;
    short* wfq1 = wf + 2*WF_MAT_SHORTS;
    short* wfv1 = wf + 3*WF_MAT_SHORTS;
    short* wfo1 = wf + 4*WF_MAT_SHORTS;
    short* wf1  = wf + 5*WF_MAT_SHORTS;
    short* wf2  = wf + 6*WF_MAT_SHORTS;

    k_wprep<<<dim3(288,7), 256, 0, stream>>>(Wv, Wo, Wq + MO, Wv + MO, Wo + MO, W1, W2, wf);
    k_prep<<<144, 256, 0, stream>>>(token, ln1g, ln1b, Wq, bq, Wk, bk, qk0T, qbk0);
    k_pool2<<<dim3(320,24), 256, 0, stream>>>(feats, boxes, Pbuf);
    k_attn0<<<320, 256, 0, stream>>>(Pbuf, qk0T, qbk0, sbuf);
    k_mgemm<1,0><<<dim3(20,12), 256, 0, stream>>>(sbuf, wfv0, bv, obuf);
    k_mgemm<0,0><<<dim3(20,12), 256, 0, stream>>>(obuf, wfo0, bo, ubuf);
    k_lnmix<<<32, 256, 0, stream>>>(ubuf, ln2g, ln2b, Wmix, bmix, xbuf);
    k_mgemm<0,0><<<dim3(20,12), 256, 0, stream>>>(xbuf, wfq1, bq + 768, qf1);
    k_qk1<<<dim3(10,12,12), 256, 0, stream>>>(qf1, Wk + MO, qk1);
    k_attn1<<<320, 256, 0, stream>>>(tmpl, qf1, bk + 768, qk1, sbuf);
    k_mgemm<1,0><<<dim3(20,12), 256, 0, stream>>>(sbuf, wfv1, bv + 768, obuf);
    k_mgemm<0,0><<<dim3(20,12), 256, 0, stream>>>(obuf, wfo1, bo + 768, ubuf);
    k_lnmix<<<32, 256, 0, stream>>>(ubuf, ln2g + 768, ln2b + 768, Wmix + 100, bmix + 10, xbuf);
    k_mgemm<0,1><<<dim3(20,12), 256, 0, stream>>>(xbuf, wf1, b1v, h1b);
    k_mgemm<0,1><<<dim3(20,12), 256, 0, stream>>>(h1b, wf2, b2v, h2b);
    k_head<<<320, 256, 0, stream>>>(h2b, W3, b3v, out);
}

// Round 4
// 363.273 us; speedup vs baseline: 1.1688x; 1.1128x over previous
//
#include <hip/hip_runtime.h>
#include <cstdint>
#include <cstddef>

namespace {

constexpr float kScale = 0.03608439182435161f; // 768^-0.5
constexpr float kEps   = 1e-5f;

// workspace offsets (in floats)
constexpr size_t OFF_QK0T = 0;                       // 12*768
constexpr size_t OFF_QBK0 = 9216;                    // 12
constexpr size_t OFF_S    = 16384;                   // 320*12*768 (s0, later s1)
constexpr size_t OFF_QK1  = OFF_S   + 2949120;       // 320*12*768
constexpr size_t OFF_O    = OFF_QK1 + 2949120;       // 320*768
constexpr size_t OFF_U    = OFF_O   + 245760;
constexpr size_t OFF_X    = OFF_U   + 245760;
constexpr size_t OFF_QF1  = OFF_X   + 245760;
constexpr size_t OFF_H1   = OFF_QF1 + 245760;
constexpr size_t OFF_H2   = OFF_H1  + 245760;
constexpr size_t OFF_WF   = OFF_H2  + 245760;        // bf16 frag weights (shorts)
constexpr size_t WF_MAT_SHORTS = 1179648;            // 24*48*2*64*8
constexpr size_t OFF_P    = OFF_WF + (7*WF_MAT_SHORTS)/2; // P[320][16][768]

typedef short short8v __attribute__((ext_vector_type(8)));
typedef float float4v __attribute__((ext_vector_type(4)));

union BP  { int4 i4; short8v s8; };
union S4P { int2 i2; short s[4]; };

__device__ __forceinline__ void splitBf(float a, short &h, short &l){
    unsigned u = __float_as_uint(a);
    h = (short)(u >> 16);
    float r = a - __uint_as_float(u & 0xFFFF0000u);
    l = (short)(__float_as_uint(r) >> 16);
}

__device__ __forceinline__ float Gf(float t){
    float tc = fminf(fmaxf(t, -1.f), 1.f);
    return 0.5f + tc * (1.f - 0.5f * fabsf(tc));
}

__device__ __forceinline__ float blockReduce256(float v, float* red){
    #pragma unroll
    for (int off = 1; off < 64; off <<= 1) v += __shfl_xor(v, off);
    __syncthreads();
    if ((threadIdx.x & 63) == 0) red[threadIdx.x >> 6] = v;
    __syncthreads();
    return red[0] + red[1] + red[2] + red[3];
}

// ---------------------------------------------------------------------------
// k_prepall: grid 2160.
//  blocks [0,2016): wprep — convert 7 weight matrices to MFMA frag bf16 hi/lo
//    WF[mat][kt(24)][nb(48)][hl(2)][lane(64)][e(8)]
//    frag map: k = kt*32 + (l>>4)*4 + (e&3) + 16*(e>>2), n = nb*16 + (l&15)
//  blocks [2016,2160): prep — x0=LN(token), qfull0, qbk0[h], qk0T[h][c]
// ---------------------------------------------------------------------------
__global__ __launch_bounds__(256) void k_prepall(
        const float* __restrict__ w0, const float* __restrict__ w1,
        const float* __restrict__ w2, const float* __restrict__ w3,
        const float* __restrict__ w4, const float* __restrict__ w5,
        const float* __restrict__ w6, short* __restrict__ WF,
        const float* __restrict__ token, const float* __restrict__ g1,
        const float* __restrict__ b1,    const float* __restrict__ Wq0,
        const float* __restrict__ bq0,   const float* __restrict__ Wk0,
        const float* __restrict__ bk0,
        float* __restrict__ qk0T, float* __restrict__ qbk0){
    __shared__ float x0l[768];
    __shared__ float red[8];
    __shared__ float qfp[4][64];
    __shared__ float qfl[64];
    __shared__ float Ws[64][68];
    const int gb = blockIdx.x;
    const int tid = threadIdx.x;
    const int l = tid & 63;

    if (gb < 2016){
        const float* Wsel[7] = {w0,w1,w2,w3,w4,w5,w6};
        const int mat = gb / 288;
        const int bxx = gb - mat*288;
        const float* W = Wsel[mat];
        const int unit = bxx * 4 + (tid >> 6); // 0..1151
        const int kt = unit / 48, nb = unit % 48;
        const int n = nb*16 + (l & 15);
        const int kb = kt*32 + ((l >> 4) << 2);
        S4P hi0, hi1, lo0, lo1;
        #pragma unroll
        for (int e = 0; e < 4; ++e){
            float a = W[(size_t)(kb + e) * 768 + n];
            splitBf(a, hi0.s[e], lo0.s[e]);
            float b = W[(size_t)(kb + 16 + e) * 768 + n];
            splitBf(b, hi1.s[e], lo1.s[e]);
        }
        size_t base = (size_t)mat * WF_MAT_SHORTS + (size_t)unit * 1024 + (size_t)l * 8;
        *(int2*)(WF + base)            = hi0.i2;
        *(int2*)(WF + base + 4)        = hi1.i2;
        *(int2*)(WF + base + 512)      = lo0.i2;
        *(int2*)(WF + base + 512 + 4)  = lo1.i2;
        return;
    }

    const int pb = gb - 2016;
    const int h  = pb / 12;
    const int ct = pb % 12;

    float v0 = token[tid], v1 = token[tid+256], v2 = token[tid+512];
    float s = blockReduce256(v0+v1+v2, red);
    float m = s * (1.f/768.f);
    float d0 = v0-m, d1 = v1-m, d2 = v2-m;
    float qv = blockReduce256(d0*d0+d1*d1+d2*d2, red);
    float rs = rsqrtf(qv*(1.f/768.f) + kEps);
    x0l[tid]     = d0*rs*g1[tid]     + b1[tid];
    x0l[tid+256] = d1*rs*g1[tid+256] + b1[tid+256];
    x0l[tid+512] = d2*rs*g1[tid+512] + b1[tid+512];
    __syncthreads();

    {
        int dl = tid & 63, part = tid >> 6;
        int d = h*64 + dl;
        float a = 0.f;
        for (int c = part*192; c < part*192 + 192; ++c)
            a += x0l[c] * Wq0[(size_t)c*768 + d];
        qfp[part][dl] = a;
    }
    __syncthreads();
    if (tid < 64){
        int d = h*64 + tid;
        qfl[tid] = qfp[0][tid]+qfp[1][tid]+qfp[2][tid]+qfp[3][tid] + bq0[d];
    }
    __syncthreads();
    if (ct == 0 && tid < 64){
        float v = qfl[tid] * bk0[h*64 + tid];
        #pragma unroll
        for (int off = 1; off < 64; off <<= 1) v += __shfl_xor(v, off);
        if (tid == 0) qbk0[h] = v;
    }
    #pragma unroll
    for (int i = 0; i < 4; ++i){
        int f = tid + i*256; int cl = f >> 4, dd = (f & 15)*4;
        float4 v = *(const float4*)(Wk0 + (size_t)(ct*64+cl)*768 + h*64 + dd);
        *(float4*)&Ws[cl][dd] = v;
    }
    __syncthreads();
    {
        int cl = tid >> 2, part = tid & 3;
        float a = 0.f;
        #pragma unroll
        for (int jj = 0; jj < 16; ++jj){
            int dd = part*16 + jj;
            a += Ws[cl][dd] * qfl[dd];
        }
        a += __shfl_xor(a, 1); a += __shfl_xor(a, 2);
        if (part == 0) qk0T[h*768 + ct*64 + cl] = a;
    }
}

// ---------------------------------------------------------------------------
// k_mgemm: C = act(bias + A[320x768] @ W[768x768]) via bf16 hi/lo MFMA.
// 512 threads (8 waves = 2 m-halves x 4 nb), grid (10,12): 32x64 tile,
// BK=64 (one barrier per 64-K step), double-buffered LDS A-frags.
// HG: A row = (m*12 + blockIdx.y)*768 (head-gathered s buffer).
// ---------------------------------------------------------------------------
template<int HG, int RELU>
__global__ __launch_bounds__(512) void k_mgemm(
        const float* __restrict__ A, const short* __restrict__ WFm,
        const float* __restrict__ bias, float* __restrict__ C){
    __shared__ short AF[2][2][2][2][64][8]; // [buf][fs(k32)][fm(m16)][hl][lane][e]
    const int h   = blockIdx.y;
    const int m0  = blockIdx.x * 32;
    const int tid = threadIdx.x;
    const int l   = tid & 63;
    const int w   = tid >> 6;
    const int wm  = w >> 2, wn = w & 3;

    // staging role: each of 512 threads stages one float4 of the 32x64 A tile
    const int srow = tid >> 4;        // 0..31
    const int sk4  = tid & 15;        // 0..15 (k4 index within 64-K)
    const int sfs  = sk4 >> 3;        // k32 half
    const int ss   = sk4 & 7;         // k4 within 32
    const int sfm  = srow >> 4;
    const int slane = (srow & 15) + 16 * (ss & 3);
    const int seb   = 4 * (ss >> 2);
    const float* aRow = HG ? (A + ((size_t)(m0 + srow) * 12 + h) * 768)
                           : (A + (size_t)(m0 + srow) * 768);

    const int nb = h * 4 + wn;
    const short* WB = WFm + (size_t)nb * 1024 + (size_t)l * 8;

    float4v acc = {0.f,0.f,0.f,0.f};

    // prologue: stage K-step 0, load B for K-step 0
    {
        float4 a0 = *(const float4*)(aRow + sk4 * 4);
        S4P hi, lo;
        splitBf(a0.x, hi.s[0], lo.s[0]); splitBf(a0.y, hi.s[1], lo.s[1]);
        splitBf(a0.z, hi.s[2], lo.s[2]); splitBf(a0.w, hi.s[3], lo.s[3]);
        *(int2*)&AF[0][sfs][sfm][0][slane][seb] = hi.i2;
        *(int2*)&AF[0][sfs][sfm][1][slane][seb] = lo.i2;
    }
    BP bh0, bl0, bh1, bl1;
    bh0.i4 = *(const int4*)(WB);
    bl0.i4 = *(const int4*)(WB + 512);
    bh1.i4 = *(const int4*)(WB + 49152);
    bl1.i4 = *(const int4*)(WB + 49152 + 512);
    __syncthreads();

    #pragma unroll 1
    for (int kt = 0; kt < 12; ++kt){
        const int cur = kt & 1;
        float4 aN;
        if (kt < 11) aN = *(const float4*)(aRow + (kt+1) * 64 + sk4 * 4);
        BP cbh0 = bh0, cbl0 = bl0, cbh1 = bh1, cbl1 = bl1;
        if (kt < 11){
            const short* wb = WB + (size_t)(2*kt + 2) * 49152;
            bh0.i4 = *(const int4*)(wb);
            bl0.i4 = *(const int4*)(wb + 512);
            bh1.i4 = *(const int4*)(wb + 49152);
            bl1.i4 = *(const int4*)(wb + 49152 + 512);
        }
        short8v ah0 = *(short8v*)&AF[cur][0][wm][0][l][0];
        short8v al0 = *(short8v*)&AF[cur][0][wm][1][l][0];
        short8v ah1 = *(short8v*)&AF[cur][1][wm][0][l][0];
        short8v al1 = *(short8v*)&AF[cur][1][wm][1][l][0];
        acc = __builtin_amdgcn_mfma_f32_16x16x32_bf16(ah0, cbh0.s8, acc, 0, 0, 0);
        acc = __builtin_amdgcn_mfma_f32_16x16x32_bf16(al0, cbh0.s8, acc, 0, 0, 0);
        acc = __builtin_amdgcn_mfma_f32_16x16x32_bf16(ah0, cbl0.s8, acc, 0, 0, 0);
        acc = __builtin_amdgcn_mfma_f32_16x16x32_bf16(ah1, cbh1.s8, acc, 0, 0, 0);
        acc = __builtin_amdgcn_mfma_f32_16x16x32_bf16(al1, cbh1.s8, acc, 0, 0, 0);
        acc = __builtin_amdgcn_mfma_f32_16x16x32_bf16(ah1, cbl1.s8, acc, 0, 0, 0);
        if (kt < 11){
            S4P hi, lo;
            splitBf(aN.x, hi.s[0], lo.s[0]); splitBf(aN.y, hi.s[1], lo.s[1]);
            splitBf(aN.z, hi.s[2], lo.s[2]); splitBf(aN.w, hi.s[3], lo.s[3]);
            *(int2*)&AF[cur ^ 1][sfs][sfm][0][slane][seb] = hi.i2;
            *(int2*)&AF[cur ^ 1][sfs][sfm][1][slane][seb] = lo.i2;
        }
        __syncthreads();
    }

    const int col = h * 64 + wn * 16 + (l & 15);
    const float bb = bias[col];
    #pragma unroll
    for (int reg = 0; reg < 4; ++reg){
        int row = m0 + wm * 16 + ((l >> 4) << 2) + reg;
        float v = acc[reg] + bb;
        if (RELU) v = fmaxf(v, 0.f);
        C[(size_t)row * 768 + col] = v;
    }
}

// ---------------------------------------------------------------------------
// k_pool2: grid (320, 24). One ROI x 32 channels per block. Row-capped (12)
// coalesced staging into 37 KB LDS (4 blocks/CU), PrRoI pooling -> P[r][t][c].
// ---------------------------------------------------------------------------
__global__ __launch_bounds__(256) void k_pool2(
        const float* __restrict__ feats, const float* __restrict__ boxes,
        float* __restrict__ P){
    __shared__ float Xs[32*292];   // [c][12 rows][24 w] stride 292
    __shared__ float wxp[24][4];
    __shared__ float wyp[24][4];
    __shared__ int   rng[2];
    __shared__ float areaInvS;
    const int r = blockIdx.x, cc = blockIdx.y * 32, tid = threadIdx.x;

    float bx0 = boxes[r*4+0]*24.f, by0 = boxes[r*4+1]*24.f;
    float bx1 = boxes[r*4+2]*24.f, by1 = boxes[r*4+3]*24.f;
    float bw = (bx1-bx0)*0.25f, bh = (by1-by0)*0.25f;
    if (tid == 0){
        int hlo = (int)floorf(by0) - 1; if (hlo < 0) hlo = 0;
        int hhi = (int)floorf(by1) + 1; if (hhi > 23) hhi = 23;
        rng[0] = hlo; rng[1] = hhi - hlo + 1;
        areaInvS = 1.f / fmaxf(bw*bh, 1e-8f);
    }
    if (tid < 24){
        int w = tid;
        #pragma unroll
        for (int q = 0; q < 4; ++q){
            float e0 = bx0 + q*bw, e1 = e0 + bw;
            wxp[w][q] = Gf(e1 - (float)w) - Gf(e0 - (float)w);
        }
    } else if (tid < 48){
        int hh = tid - 24;
        #pragma unroll
        for (int p = 0; p < 4; ++p){
            float e0 = by0 + p*bh, e1 = e0 + bh;
            wyp[hh][p] = Gf(e1 - (float)hh) - Gf(e0 - (float)hh);
        }
    }
    __syncthreads();
    const int hlo = rng[0], nr = rng[1];
    const float aInv = areaInvS;
    const int j = tid & 7;
    const int cl = tid >> 3;

    float acc[16];
    #pragma unroll
    for (int k = 0; k < 16; ++k) acc[k] = 0.f;

    for (int rb = 0; rb < nr; rb += 12){
        const int nrl = (nr - rb < 12) ? (nr - rb) : 12;
        const int nf4 = nrl * 192;
        __syncthreads();
        for (int idx = tid; idx < nf4; idx += 256){
            int ri  = idx / 192;
            int rem = idx - ri * 192;
            int c2  = rem / 6;
            int w4  = rem - c2 * 6;
            float4 v = *(const float4*)(feats + ((size_t)(r*768 + cc + c2))*576
                                        + (hlo + rb + ri)*24 + w4*4);
            *(float4*)&Xs[c2*292 + ri*24 + w4*4] = v;
        }
        __syncthreads();
        for (int rl = j; rl < nrl; rl += 8){
            const float* xr = &Xs[cl*292 + rl*24];
            float z[4] = {0.f,0.f,0.f,0.f};
            #pragma unroll
            for (int w4 = 0; w4 < 6; ++w4){
                float4 xv = *(const float4*)(xr + w4*4);
                float xa[4] = {xv.x, xv.y, xv.z, xv.w};
                #pragma unroll
                for (int k = 0; k < 4; ++k){
                    float4 wv = *(const float4*)&wxp[w4*4+k][0];
                    z[0] += wv.x*xa[k]; z[1] += wv.y*xa[k];
                    z[2] += wv.z*xa[k]; z[3] += wv.w*xa[k];
                }
            }
            float4 wyv = *(const float4*)&wyp[hlo+rb+rl][0];
            float wya[4] = {wyv.x, wyv.y, wyv.z, wyv.w};
            #pragma unroll
            for (int p = 0; p < 4; ++p)
                #pragma unroll
                for (int q = 0; q < 4; ++q)
                    acc[p*4+q] += wya[p]*z[q];
        }
    }
    #pragma unroll
    for (int k = 0; k < 16; ++k){
        acc[k] += __shfl_xor(acc[k], 1);
        acc[k] += __shfl_xor(acc[k], 2);
        acc[k] += __shfl_xor(acc[k], 4);
    }
    float o0 = acc[0], o1 = acc[8];
    #pragma unroll
    for (int k = 1; k < 8; ++k){
        if (j == k){ o0 = acc[k]; o1 = acc[k+8]; }
    }
    P[((size_t)r*16 + j)*768 + cc + cl]     = o0 * aInv;
    P[((size_t)r*16 + j + 8)*768 + cc + cl] = o1 * aInv;
}

// ---------------------------------------------------------------------------
// k_attn0: grid 320. Stage P[r] (16x768), branch-0 logits/softmax -> s0.
// ---------------------------------------------------------------------------
__global__ __launch_bounds__(256) void k_attn0(
        const float* __restrict__ P, const float* __restrict__ qk0T,
        const float* __restrict__ qbk0g, float* __restrict__ s0){
    __shared__ float P2[16][776];
    __shared__ float logitsL[12][17];
    __shared__ float attnT[16][12];
    const int r = blockIdx.x, tid = threadIdx.x;

    #pragma unroll
    for (int i = 0; i < 12; ++i){
        int f = tid + i*256;
        int t = f / 192, c4 = f - t*192;
        float4 v = *(const float4*)(P + ((size_t)r*16 + t)*768 + c4*4);
        *(float4*)&P2[t][c4*4] = v;
    }
    __syncthreads();

    if (tid < 192){
        int h = tid >> 4, t = tid & 15;
        float a = qbk0g[h];
        const float* qrow = qk0T + h*768;
        #pragma unroll 4
        for (int c4 = 0; c4 < 192; ++c4){
            float4 qv = *(const float4*)(qrow + c4*4);
            float4 pv = *(const float4*)&P2[t][c4*4];
            a += qv.x*pv.x + qv.y*pv.y + qv.z*pv.z + qv.w*pv.w;
        }
        logitsL[h][t] = a * kScale;
    }
    __syncthreads();
    if (tid < 12){
        float mx = -1e30f;
        for (int t = 0; t < 16; ++t) mx = fmaxf(mx, logitsL[tid][t]);
        float ss = 0.f;
        for (int t = 0; t < 16; ++t){
            float e = expf(logitsL[tid][t] - mx);
            attnT[t][tid] = e; ss += e;
        }
        float rsn = 1.f/ss;
        for (int t = 0; t < 16; ++t) attnT[t][tid] *= rsn;
    }
    __syncthreads();
    #pragma unroll
    for (int s3 = 0; s3 < 3; ++s3){
        int c = tid + s3*256;
        float a12[12];
        #pragma unroll
        for (int h = 0; h < 12; ++h) a12[h] = 0.f;
        #pragma unroll
        for (int t = 0; t < 16; ++t){
            float x = P2[t][c];
            float4 a0 = *(const float4*)&attnT[t][0];
            float4 a1 = *(const float4*)&attnT[t][4];
            float4 a2 = *(const float4*)&attnT[t][8];
            a12[0] += a0.x*x; a12[1] += a0.y*x; a12[2]  += a0.z*x; a12[3]  += a0.w*x;
            a12[4] += a1.x*x; a12[5] += a1.y*x; a12[6]  += a1.z*x; a12[7]  += a1.w*x;
            a12[8] += a2.x*x; a12[9] += a2.y*x; a12[10] += a2.z*x; a12[11] += a2.w*x;
        }
        #pragma unroll
        for (int h = 0; h < 12; ++h)
            s0[((size_t)r*12 + h)*768 + c] = a12[h];
    }
}

// ---------------------------------------------------------------------------
// k_qk1: qk1[r][h][c] = sum_{dl<64} qfull1[r, h*64+dl] * Wk1[c, h*64+dl]
// ---------------------------------------------------------------------------
__global__ __launch_bounds__(256) void k_qk1(
        const float* __restrict__ qf1, const float* __restrict__ Wk1,
        float* __restrict__ qk1){
    __shared__ float As[32][68];
    __shared__ float Bs[64][68]; // [d][c]
    const int r0 = blockIdx.x * 32, h = blockIdx.y, c0 = blockIdx.z * 64;
    const int tid = threadIdx.x;
    #pragma unroll
    for (int i = 0; i < 2; ++i){
        int f = tid + i*256; int ml = f >> 4, kk = (f & 15)*4;
        *(float4*)&As[ml][kk] =
            *(const float4*)(qf1 + (size_t)(r0+ml)*768 + h*64 + kk);
    }
    #pragma unroll
    for (int i = 0; i < 4; ++i){
        int f = tid + i*256; int cl = f >> 4, dd = (f & 15)*4;
        float4 v = *(const float4*)(Wk1 + (size_t)(c0+cl)*768 + h*64 + dd);
        Bs[dd+0][cl] = v.x; Bs[dd+1][cl] = v.y;
        Bs[dd+2][cl] = v.z; Bs[dd+3][cl] = v.w;
    }
    __syncthreads();
    const int tn = tid & 15, tm = tid >> 4;
    float acc0[4] = {0.f,0.f,0.f,0.f};
    float acc1[4] = {0.f,0.f,0.f,0.f};
    #pragma unroll
    for (int k4 = 0; k4 < 16; ++k4){
        float4 av0 = *(const float4*)&As[tm*2+0][k4*4];
        float4 av1 = *(const float4*)&As[tm*2+1][k4*4];
        float a0a[4] = {av0.x, av0.y, av0.z, av0.w};
        float a1a[4] = {av1.x, av1.y, av1.z, av1.w};
        #pragma unroll
        for (int jj = 0; jj < 4; ++jj){
            float4 bv = *(const float4*)&Bs[k4*4+jj][tn*4];
            acc0[0] += a0a[jj]*bv.x; acc0[1] += a0a[jj]*bv.y;
            acc0[2] += a0a[jj]*bv.z; acc0[3] += a0a[jj]*bv.w;
            acc1[0] += a1a[jj]*bv.x; acc1[1] += a1a[jj]*bv.y;
            acc1[2] += a1a[jj]*bv.z; acc1[3] += a1a[jj]*bv.w;
        }
    }
    float4 o0; o0.x=acc0[0]; o0.y=acc0[1]; o0.z=acc0[2]; o0.w=acc0[3];
    float4 o1; o1.x=acc1[0]; o1.y=acc1[1]; o1.z=acc1[2]; o1.w=acc1[3];
    *(float4*)(qk1 + ((size_t)(r0+tm*2+0)*12 + h)*768 + c0 + tn*4) = o0;
    *(float4*)(qk1 + ((size_t)(r0+tm*2+1)*12 + h)*768 + c0 + tn*4) = o1;
}

// ---------------------------------------------------------------------------
// k_attn1: grid 320 (one ROI). Branch-1 logits/softmax/s1 against template.
// ---------------------------------------------------------------------------
__global__ __launch_bounds__(256) void k_attn1(
        const float* __restrict__ tmpl, const float* __restrict__ qf1,
        const float* __restrict__ bk1,  const float* __restrict__ qk1,
        float* __restrict__ s1){
    __shared__ float Tc[192][68];
    __shared__ float logitsT[64][13];
    __shared__ float attnH[12][64];
    __shared__ float qbk[12];
    const int r = blockIdx.x, tid = threadIdx.x;
    const float* tp = tmpl + (size_t)r*768*64;

    if (tid < 192){
        int h = tid >> 4, pp = tid & 15;
        float v = 0.f;
        #pragma unroll
        for (int jj = 0; jj < 4; ++jj){
            int d = h*64 + pp*4 + jj;
            v += bk1[d] * qf1[(size_t)r*768 + d];
        }
        v += __shfl_xor(v,1); v += __shfl_xor(v,2);
        v += __shfl_xor(v,4); v += __shfl_xor(v,8);
        if (pp == 0) qbk[h] = v;
    }
    __syncthreads();
    float lacc[3];
    #pragma unroll
    for (int s = 0; s < 3; ++s){
        int task = tid + s*256;
        lacc[s] = qbk[task >> 6];
    }
    for (int cb = 0; cb < 4; ++cb){
        #pragma unroll
        for (int i = 0; i < 12; ++i){
            int f = tid + i*256; int cl = f >> 4, t4 = (f & 15)*4;
            *(float4*)&Tc[cl][t4] =
                *(const float4*)(tp + (size_t)(cb*192 + cl)*64 + t4);
        }
        __syncthreads();
        #pragma unroll
        for (int s = 0; s < 3; ++s){
            int task = tid + s*256;
            int h = task >> 6, t = task & 63;
            const float* qrow = qk1 + ((size_t)r*12 + h)*768 + cb*192;
            float a = 0.f;
            #pragma unroll 4
            for (int c4 = 0; c4 < 48; ++c4){
                float4 qv = *(const float4*)(qrow + c4*4);
                a += qv.x*Tc[c4*4+0][t] + qv.y*Tc[c4*4+1][t]
                   + qv.z*Tc[c4*4+2][t] + qv.w*Tc[c4*4+3][t];
            }
            lacc[s] += a;
        }
        __syncthreads();
    }
    #pragma unroll
    for (int s = 0; s < 3; ++s){
        int task = tid + s*256;
        logitsT[task & 63][task >> 6] = lacc[s] * kScale;
    }
    __syncthreads();
    if (tid < 12){
        float mx = -1e30f;
        for (int t = 0; t < 64; ++t) mx = fmaxf(mx, logitsT[t][tid]);
        float ss = 0.f;
        for (int t = 0; t < 64; ++t){
            float e = expf(logitsT[t][tid] - mx);
            attnH[tid][t] = e; ss += e;
        }
        float rsn = 1.f/ss;
        for (int t = 0; t < 64; ++t) attnH[tid][t] *= rsn;
    }
    __syncthreads();
    for (int cb = 0; cb < 4; ++cb){
        #pragma unroll
        for (int i = 0; i < 12; ++i){
            int f = tid + i*256; int cl = f >> 4, t4 = (f & 15)*4;
            *(float4*)&Tc[cl][t4] =
                *(const float4*)(tp + (size_t)(cb*192 + cl)*64 + t4);
        }
        __syncthreads();
        if (tid < 192){
            float4 trow[16];
            #pragma unroll
            for (int t4 = 0; t4 < 16; ++t4)
                trow[t4] = *(const float4*)&Tc[tid][t4*4];
            int c = cb*192 + tid;
            #pragma unroll
            for (int h = 0; h < 12; ++h){
                float a = 0.f;
                #pragma unroll
                for (int t4 = 0; t4 < 16; ++t4){
                    float4 avv = *(const float4*)&attnH[h][t4*4];
                    float4 tv = trow[t4];
                    a += avv.x*tv.x + avv.y*tv.y + avv.z*tv.z + avv.w*tv.w;
                }
                s1[((size_t)r*12 + h)*768 + c] = a;
            }
        }
        __syncthreads();
    }
}

// ---------------------------------------------------------------------------
// k_lnmix: grid 32 (one b). LN(u[n,b,:]) with ln2 params, then N-mix with Wmix.
// ---------------------------------------------------------------------------
__global__ __launch_bounds__(256) void k_lnmix(
        const float* __restrict__ u, const float* __restrict__ g,
        const float* __restrict__ bta, const float* __restrict__ Wmix,
        const float* __restrict__ bmix, float* __restrict__ xout){
    __shared__ float lnl[10][768];
    __shared__ float red[8];
    __shared__ float wm[100];
    __shared__ float bm[10];
    const int b = blockIdx.x, tid = threadIdx.x;
    if (tid < 100) wm[tid] = Wmix[tid];
    if (tid < 10)  bm[tid] = bmix[tid];
    for (int n = 0; n < 10; ++n){
        const float* row = u + (size_t)(n*32 + b)*768;
        float v0 = row[tid], v1 = row[tid+256], v2 = row[tid+512];
        float s = blockReduce256(v0+v1+v2, red);
        float m = s * (1.f/768.f);
        float d0 = v0-m, d1 = v1-m, d2 = v2-m;
        float qv = blockReduce256(d0*d0+d1*d1+d2*d2, red);
        float rs = rsqrtf(qv*(1.f/768.f) + kEps);
        lnl[n][tid]     = d0*rs*g[tid]     + bta[tid];
        lnl[n][tid+256] = d1*rs*g[tid+256] + bta[tid+256];
        lnl[n][tid+512] = d2*rs*g[tid+512] + bta[tid+512];
    }
    __syncthreads();
    #pragma unroll
    for (int s3 = 0; s3 < 3; ++s3){
        int c = tid + s3*256;
        float col[10];
        #pragma unroll
        for (int n = 0; n < 10; ++n) col[n] = lnl[n][c];
        #pragma unroll
        for (int np = 0; np < 10; ++np){
            float a = bm[np];
            #pragma unroll
            for (int n = 0; n < 10; ++n) a += col[n]*wm[n*10+np];
            xout[(size_t)(np*32 + b)*768 + c] = a;
        }
    }
}

// ---------------------------------------------------------------------------
// k_head: out[r] = b3 + sum_e h2[r][e]*W3[e]
// ---------------------------------------------------------------------------
__global__ __launch_bounds__(256) void k_head(
        const float* __restrict__ h2v, const float* __restrict__ W3,
        const float* __restrict__ b3, float* __restrict__ out){
    __shared__ float red[8];
    const int r = blockIdx.x, tid = threadIdx.x;
    const float* row = h2v + (size_t)r*768;
    float a = row[tid]*W3[tid] + row[tid+256]*W3[tid+256] + row[tid+512]*W3[tid+512];
    a = blockReduce256(a, red);
    if (tid == 0) out[r] = a + b3[0];
}

} // anonymous namespace

extern "C" void kernel_launch(void* const* d_in, const int* in_sizes, int n_in,
                              void* d_out, int out_size, void* d_ws, size_t ws_size,
                              hipStream_t stream){
    const float* feats = (const float*)d_in[0];
    const float* tmpl  = (const float*)d_in[1];
    const float* boxes = (const float*)d_in[2];
    const float* token = (const float*)d_in[3];
    const float* ln1g  = (const float*)d_in[4];
    const float* ln1b  = (const float*)d_in[5];
    const float* Wq    = (const float*)d_in[6];
    const float* bq    = (const float*)d_in[7];
    const float* Wk    = (const float*)d_in[8];
    const float* bk    = (const float*)d_in[9];
    const float* Wv    = (const float*)d_in[10];
    const float* bv    = (const float*)d_in[11];
    const float* Wo    = (const float*)d_in[12];
    const float* bo    = (const float*)d_in[13];
    const float* ln2g  = (const float*)d_in[14];
    const float* ln2b  = (const float*)d_in[15];
    const float* Wmix  = (const float*)d_in[16];
    const float* bmix  = (const float*)d_in[17];
    const float* W1    = (const float*)d_in[18];
    const float* b1v   = (const float*)d_in[19];
    const float* W2    = (const float*)d_in[20];
    const float* b2v   = (const float*)d_in[21];
    const float* W3    = (const float*)d_in[22];
    const float* b3v   = (const float*)d_in[23];
    float* ws  = (float*)d_ws;
    float* out = (float*)d_out;

    float* qk0T = ws + OFF_QK0T;
    float* qbk0 = ws + OFF_QBK0;
    float* sbuf = ws + OFF_S;
    float* qk1  = ws + OFF_QK1;
    float* obuf = ws + OFF_O;
    float* ubuf = ws + OFF_U;
    float* xbuf = ws + OFF_X;
    float* qf1  = ws + OFF_QF1;
    float* h1b  = ws + OFF_H1;
    float* h2b  = ws + OFF_H2;
    short* wf   = (short*)(ws + OFF_WF);
    float* Pbuf = ws + OFF_P;

    const size_t MO = 589824; // 768*768
    // frag-weight order: 0:Wv0 1:Wo0 2:Wq1 3:Wv1 4:Wo1 5:W1 6:W2
    short* wfv0 = wf + 0*WF_MAT_SHORTS;
    short* wfo0 = wf + 1*WF_MAT_SHORTS;
    short* wfq1 = wf + 2*WF_MAT_SHORTS;
    short* wfv1 = wf + 3*WF_MAT_SHORTS;
    short* wfo1 = wf + 4*WF_MAT_SHORTS;
    short* wf1  = wf + 5*WF_MAT_SHORTS;
    short* wf2  = wf + 6*WF_MAT_SHORTS;

    k_prepall<<<2160, 256, 0, stream>>>(Wv, Wo, Wq + MO, Wv + MO, Wo + MO, W1, W2, wf,
                                        token, ln1g, ln1b, Wq, bq, Wk, bk, qk0T, qbk0);
    k_pool2<<<dim3(320,24), 256, 0, stream>>>(feats, boxes, Pbuf);
    k_attn0<<<320, 256, 0, stream>>>(Pbuf, qk0T, qbk0, sbuf);
    k_mgemm<1,0><<<dim3(10,12), 512, 0, stream>>>(sbuf, wfv0, bv, obuf);
    k_mgemm<0,0><<<dim3(10,12), 512, 0, stream>>>(obuf, wfo0, bo, ubuf);
    k_lnmix<<<32, 256, 0, stream>>>(ubuf, ln2g, ln2b, Wmix, bmix, xbuf);
    k_mgemm<0,0><<<dim3(10,12), 512, 0, stream>>>(xbuf, wfq1, bq + 768, qf1);
    k_qk1<<<dim3(10,12,12), 256, 0, stream>>>(qf1, Wk + MO, qk1);
    k_attn1<<<320, 256, 0, stream>>>(tmpl, qf1, bk + 768, qk1, sbuf);
    k_mgemm<1,0><<<dim3(10,12), 512, 0, stream>>>(sbuf, wfv1, bv + 768, obuf);
    k_mgemm<0,0><<<dim3(10,12), 512, 0, stream>>>(obuf, wfo1, bo + 768, ubuf);
    k_lnmix<<<32, 256, 0, stream>>>(ubuf, ln2g + 768, ln2b + 768, Wmix + 100, bmix + 10, xbuf);
    k_mgemm<0,1><<<dim3(10,12), 512, 0, stream>>>(xbuf, wf1, b1v, h1b);
    k_mgemm<0,1><<<dim3(10,12), 512, 0, stream>>>(h1b, wf2, b2v, h2b);
    k_head<<<320, 256, 0, stream>>>(h2b, W3, b3v, out);
}